// Round 1
// baseline (1561.729 us; speedup 1.0000x reference)
//
#include <hip/hip_runtime.h>
#include <hip/hip_bf16.h>

#define N_NODES 8192
#define BGRAPH 8
#define NPG 1024
#define DIM 256
#define NH 8
#define DHEAD 32
#define NLAYERS 2
#define INC 128
#define OUTD 64
#define NEDGE 262144
#define DFF 512
#define EPS 1e-5f

// ---------------------------------------------------------------------------
// Graph setup: degree count, inverse degree, exclusive scan, CSR fill
// ---------------------------------------------------------------------------
__global__ void k_count_deg(const int* __restrict__ dst, int* __restrict__ deg){
  int i = blockIdx.x*blockDim.x + threadIdx.x;
  int stride = gridDim.x*blockDim.x;
  for(; i<NEDGE; i+=stride) atomicAdd(&deg[dst[i]], 1);
}

__global__ void k_inv_deg(const int* __restrict__ deg, float* __restrict__ inv_deg){
  int i = blockIdx.x*blockDim.x + threadIdx.x;
  if(i<N_NODES){ int d=deg[i]; inv_deg[i] = 1.0f/(float)(d>0?d:1); }
}

// single block, 1024 threads, scans 8192 ints
__global__ void k_scan(const int* __restrict__ deg, int* __restrict__ offs){
  __shared__ int s[1024];
  int t = threadIdx.x;
  int base = t*8;
  int loc[8]; int acc=0;
  #pragma unroll
  for(int j=0;j<8;j++){ loc[j]=acc; acc += deg[base+j]; }
  s[t]=acc;
  __syncthreads();
  for(int d=1; d<1024; d<<=1){
    int v = (t>=d)? s[t-d] : 0;
    __syncthreads();
    if(t>=d) s[t]+=v;
    __syncthreads();
  }
  int pre = (t>0)? s[t-1] : 0;
  #pragma unroll
  for(int j=0;j<8;j++) offs[base+j] = pre + loc[j];
  if(t==1023) offs[N_NODES] = s[1023];
}

__global__ void k_fill_csr(const int* __restrict__ src, const int* __restrict__ dst,
                           const int* __restrict__ offs, int* __restrict__ cursor,
                           int* __restrict__ csr){
  int i = blockIdx.x*blockDim.x + threadIdx.x;
  int stride = gridDim.x*blockDim.x;
  for(; i<NEDGE; i+=stride){
    int d = dst[i];
    int p = atomicAdd(&cursor[d], 1);
    csr[offs[d]+p] = src[i];
  }
}

// one block per destination node; thread d owns channel d (coalesced rows)
__global__ __launch_bounds__(256) void k_aggregate(const float* __restrict__ h,
    const int* __restrict__ offs, const int* __restrict__ csr,
    const float* __restrict__ inv_deg, float* __restrict__ agg){
  __shared__ int sj[256];
  int n = blockIdx.x;
  int d = threadIdx.x;
  int beg=offs[n], end=offs[n+1];
  float s=0.f;
  for(int b0=beg; b0<end; b0+=256){
    int cnt = min(256, end-b0);
    __syncthreads();
    if(d<cnt) sj[d]=csr[b0+d];
    __syncthreads();
    for(int i=0;i<cnt;i++) s += h[(size_t)sj[i]*DIM + d];
  }
  agg[(size_t)n*DIM + d] = s * inv_deg[n];
}

// ---------------------------------------------------------------------------
// Generic fp32 GEMM: C[M,Nc] = A[M,K] @ W[Nc,K]^T (+bias)(+resid)(+C)(relu)
// 64x64 tile, BK=16, 256 threads, 4x4 per thread
// ---------------------------------------------------------------------------
template<bool RELU, bool ACC, bool RESID, bool BIAS>
__global__ __launch_bounds__(256) void k_gemm(const float* __restrict__ A,
    const float* __restrict__ W, const float* __restrict__ bias,
    const float* __restrict__ resid, float* __restrict__ C,
    int M, int Nc, int K)
{
  __shared__ __align__(16) float As[16][68];
  __shared__ __align__(16) float Ws[16][68];
  int bm = blockIdx.y*64, bn = blockIdx.x*64;
  int tid = threadIdx.x;
  int tx = tid & 15, ty = tid >> 4;
  float acc[4][4] = {};
  int lm = tid >> 4, lk = tid & 15;
  for(int k0=0; k0<K; k0+=16){
    __syncthreads();
    #pragma unroll
    for(int r=0;r<4;r++){
      As[lk][lm+r*16] = A[(size_t)(bm+lm+r*16)*K + k0+lk];
      Ws[lk][lm+r*16] = W[(size_t)(bn+lm+r*16)*K + k0+lk];
    }
    __syncthreads();
    #pragma unroll
    for(int k=0;k<16;k++){
      float4 a = *(const float4*)&As[k][ty*4];
      float4 b = *(const float4*)&Ws[k][tx*4];
      float av[4]={a.x,a.y,a.z,a.w};
      float bv[4]={b.x,b.y,b.z,b.w};
      #pragma unroll
      for(int i=0;i<4;i++)
        #pragma unroll
        for(int j=0;j<4;j++) acc[i][j] += av[i]*bv[j];
    }
  }
  #pragma unroll
  for(int i=0;i<4;i++){
    int m = bm + ty*4 + i;
    int n0 = bn + tx*4;
    float4 v = {acc[i][0],acc[i][1],acc[i][2],acc[i][3]};
    if(BIAS){
      float4 bb = *(const float4*)&bias[n0];
      v.x+=bb.x; v.y+=bb.y; v.z+=bb.z; v.w+=bb.w;
    }
    if(RESID){
      float4 rr = *(const float4*)&resid[(size_t)m*Nc+n0];
      v.x+=rr.x; v.y+=rr.y; v.z+=rr.z; v.w+=rr.w;
    }
    if(ACC){
      float4 cc = *(const float4*)&C[(size_t)m*Nc+n0];
      v.x+=cc.x; v.y+=cc.y; v.z+=cc.z; v.w+=cc.w;
    }
    if(RELU){
      v.x=fmaxf(v.x,0.f); v.y=fmaxf(v.y,0.f); v.z=fmaxf(v.z,0.f); v.w=fmaxf(v.w,0.f);
    }
    *(float4*)&C[(size_t)m*Nc+n0] = v;
  }
}

// ---------------------------------------------------------------------------
// BatchNorm over nodes: stats (sum/sumsq per channel) + apply
// ---------------------------------------------------------------------------
template<bool ADD>
__global__ __launch_bounds__(256) void k_bn_stats(const float* __restrict__ x,
    const float* __restrict__ add, float* __restrict__ sumb, float* __restrict__ sqb){
  int d = threadIdx.x;
  int r0 = blockIdx.x*64;
  float s=0.f, q=0.f;
  for(int r=r0; r<r0+64; ++r){
    float v = x[(size_t)r*DIM+d];
    if(ADD) v += add[(size_t)r*DIM+d];
    s += v; q += v*v;
  }
  atomicAdd(&sumb[d], s);
  atomicAdd(&sqb[d], q);
}

template<bool ADD, bool RELU_ADD_OUT>
__global__ __launch_bounds__(256) void k_bn_apply(const float* __restrict__ x,
    const float* __restrict__ add, const float* __restrict__ sumb,
    const float* __restrict__ sqb, const float* __restrict__ w,
    const float* __restrict__ b, float* __restrict__ out){
  int d = threadIdx.x;
  size_t idx = (size_t)blockIdx.x*DIM + d;
  float m = sumb[d]*(1.0f/N_NODES);
  float v = sqb[d]*(1.0f/N_NODES) - m*m;
  float rs = rsqrtf(v + EPS);
  float val = x[idx];
  if(ADD) val += add[idx];
  float y = (val - m)*rs*w[d] + b[d];
  if(RELU_ADD_OUT) out[idx] += fmaxf(y, 0.f);
  else out[idx] = y;
}

__global__ void k_add_inplace(float* __restrict__ a, const float* __restrict__ b){
  size_t i = (size_t)blockIdx.x*blockDim.x + threadIdx.x;
  a[i] += b[i];
}

// ---------------------------------------------------------------------------
// Dense per-graph multi-head attention, flash style.
// 1 lane = 1 query; block = 256 threads = 4 waves = 256 queries of one (b,h).
// grid = B*H*(NPG/256) = 256 blocks. K/V tiles of 64 keys staged in LDS.
// ---------------------------------------------------------------------------
__global__ __launch_bounds__(256) void k_attn(const float* __restrict__ qkv,
                                              float* __restrict__ attnO){
  const float scale = 0.17677669529663687f; // 1/sqrt(32)
  int bid = blockIdx.x;
  int qt = bid & 3;            // query tile (256 queries each)
  int bh = bid >> 2;
  int hh = bh & (NH-1);
  int bg = bh >> 3;
  int wave = threadIdx.x >> 6;
  int lane = threadIdx.x & 63;
  int q_local = qt*256 + wave*64 + lane;   // [0,1024)
  int n = bg*NPG + q_local;

  const float* qptr = qkv + (size_t)n*(3*DIM) + hh*DHEAD;
  float qreg[32];
  #pragma unroll
  for(int d=0; d<32; d++) qreg[d] = qptr[d]*scale;

  float m = -1e30f, s = 0.f;
  float o[32];
  #pragma unroll
  for(int d=0; d<32; d++) o[d]=0.f;

  __shared__ float Ks[64][32];
  __shared__ float Vs[64][32];
  int kbase = bg*NPG;

  for(int kt=0; kt<NPG/64; ++kt){
    __syncthreads();
    for(int i=threadIdx.x; i<64*32; i+=256){
      int j = i>>5, d = i&31;
      int kn = kbase + kt*64 + j;
      Ks[j][d] = qkv[(size_t)kn*(3*DIM) + DIM     + hh*DHEAD + d];
      Vs[j][d] = qkv[(size_t)kn*(3*DIM) + 2*DIM   + hh*DHEAD + d];
    }
    __syncthreads();
    for(int c=0; c<4; ++c){   // 4 chunks of 16 keys
      float sc[16];
      #pragma unroll
      for(int j=0;j<16;j++){
        const float* kr = Ks[c*16+j];
        float dot=0.f;
        #pragma unroll
        for(int dd=0; dd<32; dd++) dot += qreg[dd]*kr[dd];
        sc[j]=dot;
      }
      float tmax = m;
      #pragma unroll
      for(int j=0;j<16;j++) tmax = fmaxf(tmax, sc[j]);
      float alpha = __expf(m - tmax);
      m = tmax;
      s *= alpha;
      #pragma unroll
      for(int d=0; d<32; d++) o[d] *= alpha;
      #pragma unroll
      for(int j=0;j<16;j++){
        float p = __expf(sc[j]-m);
        s += p;
        const float* vr = Vs[c*16+j];
        #pragma unroll
        for(int d=0; d<32; d++) o[d] += p*vr[d];
      }
    }
  }
  float inv = 1.0f/s;
  float* op = attnO + (size_t)n*DIM + hh*DHEAD;
  #pragma unroll
  for(int d=0; d<32; d++) op[d] = o[d]*inv;
}

// ---------------------------------------------------------------------------
// Pooling + output head
// ---------------------------------------------------------------------------
__global__ void k_pool(const float* __restrict__ h, float* __restrict__ pooled){
  int b = blockIdx.x, c = blockIdx.y, d = threadIdx.x;
  int r0 = c*64;
  float s=0.f;
  for(int i=0;i<64;i++) s += h[(size_t)(b*NPG + r0 + i)*DIM + d];
  atomicAdd(&pooled[b*DIM+d], s*(1.0f/NPG));
}

__global__ void k_out(const float* __restrict__ pooled, const float* __restrict__ w_out,
                      const float* __restrict__ b_out, float* __restrict__ out){
  int t = threadIdx.x;
  if(t >= BGRAPH*OUTD) return;
  int b = t/OUTD, oc = t%OUTD;
  float s = b_out[oc];
  for(int k=0;k<DIM;k++) s += pooled[b*DIM+k]*w_out[oc*DIM+k];
  out[t] = s;
}

// ---------------------------------------------------------------------------
// Orchestration
// ---------------------------------------------------------------------------
extern "C" void kernel_launch(void* const* d_in, const int* in_sizes, int n_in,
                              void* d_out, int out_size, void* d_ws, size_t ws_size,
                              hipStream_t stream) {
  const float* x       = (const float*)d_in[0];
  const int*   edge    = (const int*)d_in[1];   // [2][E]
  const float* w_in    = (const float*)d_in[3];
  const float* b_in    = (const float*)d_in[4];
  const float* sage_wl = (const float*)d_in[5];
  const float* sage_bl = (const float*)d_in[6];
  const float* sage_wr = (const float*)d_in[7];
  const float* attn_iw = (const float*)d_in[8];
  const float* attn_ib = (const float*)d_in[9];
  const float* attn_ow = (const float*)d_in[10];
  const float* attn_ob = (const float*)d_in[11];
  const float* n1_w = (const float*)d_in[12];
  const float* n1_b = (const float*)d_in[13];
  const float* n2_w = (const float*)d_in[14];
  const float* n2_b = (const float*)d_in[15];
  const float* n3_w = (const float*)d_in[16];
  const float* n3_b = (const float*)d_in[17];
  const float* mlp_w1 = (const float*)d_in[18];
  const float* mlp_b1 = (const float*)d_in[19];
  const float* mlp_w2 = (const float*)d_in[20];
  const float* mlp_b2 = (const float*)d_in[21];
  const float* bn_w = (const float*)d_in[22];
  const float* bn_b = (const float*)d_in[23];
  const float* w_out = (const float*)d_in[24];
  const float* b_out = (const float*)d_in[25];

  float* ws = (float*)d_ws;
  const size_t ND = (size_t)N_NODES*DIM;        // 2,097,152
  float* H    = ws;
  float* bA   = ws + ND;
  float* bB   = ws + 2*ND;
  float* bC   = ws + 3*ND;
  float* bQ   = ws + 4*ND;                      // N*3D = 3*ND
  float* bH   = ws + 7*ND;                      // N*DFF = 2*ND
  float* inv_deg = ws + 9*ND;
  float* sumb = inv_deg + N_NODES;
  float* sqb  = sumb + DIM;
  float* pooled = sqb + DIM;
  int* ip = (int*)(pooled + BGRAPH*DIM);
  int* deg    = ip;
  int* cursor = ip + N_NODES;
  int* offs   = ip + 2*N_NODES;
  int* csr    = ip + 2*N_NODES + N_NODES + 8;   // offs gets N+1 (+pad)

  const int* esrc = edge;
  const int* edst = edge + NEDGE;

  // ---- graph structure (recomputed every call; ws is not persistent) ----
  hipMemsetAsync(deg, 0, N_NODES*sizeof(int), stream);
  hipMemsetAsync(cursor, 0, N_NODES*sizeof(int), stream);
  k_count_deg<<<512,256,0,stream>>>(edst, deg);
  k_inv_deg<<<(N_NODES+255)/256,256,0,stream>>>(deg, inv_deg);
  k_scan<<<1,1024,0,stream>>>(deg, offs);
  k_fill_csr<<<512,256,0,stream>>>(esrc, edst, offs, cursor, csr);

  // ---- in_proj: H = x @ w_in^T + b_in ----
  k_gemm<false,false,false,true><<<dim3(DIM/64, N_NODES/64),256,0,stream>>>(
      x, w_in, b_in, nullptr, H, N_NODES, DIM, INC);

  for(int l=0; l<NLAYERS; ++l){
    const float* wl  = sage_wl + (size_t)l*DIM*DIM;
    const float* bl  = sage_bl + (size_t)l*DIM;
    const float* wr  = sage_wr + (size_t)l*DIM*DIM;
    const float* iw  = attn_iw + (size_t)l*3*DIM*DIM;
    const float* ib  = attn_ib + (size_t)l*3*DIM;
    const float* ow  = attn_ow + (size_t)l*DIM*DIM;
    const float* ob  = attn_ob + (size_t)l*DIM;
    const float* w1  = mlp_w1 + (size_t)l*DFF*DIM;
    const float* b1  = mlp_b1 + (size_t)l*DFF;
    const float* w2  = mlp_w2 + (size_t)l*DIM*DFF;
    const float* b2  = mlp_b2 + (size_t)l*DIM;

    // SAGE: agg = segsum(H[src])/deg ; loc = agg@wl^T + bl + H@wr^T
    k_aggregate<<<N_NODES,256,0,stream>>>(H, offs, csr, inv_deg, bA);
    k_gemm<false,false,false,true><<<dim3(DIM/64, N_NODES/64),256,0,stream>>>(
        bA, wl, bl, nullptr, bB, N_NODES, DIM, DIM);
    k_gemm<false,true,false,false><<<dim3(DIM/64, N_NODES/64),256,0,stream>>>(
        H, wr, nullptr, nullptr, bB, N_NODES, DIM, DIM);
    // loc = BN1(loc + H)
    hipMemsetAsync(sumb, 0, 2*DIM*sizeof(float), stream);
    k_bn_stats<true><<<128,256,0,stream>>>(bB, H, sumb, sqb);
    k_bn_apply<true,false><<<N_NODES,256,0,stream>>>(bB, H, sumb, sqb,
        n1_w + l*DIM, n1_b + l*DIM, bB);

    // attention: qkv, flash, out-proj
    k_gemm<false,false,false,true><<<dim3(3*DIM/64, N_NODES/64),256,0,stream>>>(
        H, iw, ib, nullptr, bQ, N_NODES, 3*DIM, DIM);
    k_attn<<<BGRAPH*NH*(NPG/256),256,0,stream>>>(bQ, bC);
    k_gemm<false,false,false,true><<<dim3(DIM/64, N_NODES/64),256,0,stream>>>(
        bC, ow, ob, nullptr, bA, N_NODES, DIM, DIM);
    // glob = BN2(o + H)
    hipMemsetAsync(sumb, 0, 2*DIM*sizeof(float), stream);
    k_bn_stats<true><<<128,256,0,stream>>>(bA, H, sumb, sqb);
    k_bn_apply<true,false><<<N_NODES,256,0,stream>>>(bA, H, sumb, sqb,
        n2_w + l*DIM, n2_b + l*DIM, bA);

    // comb = loc + glob (into bB)
    k_add_inplace<<<N_NODES*DIM/256,256,0,stream>>>(bB, bA);
    // MLP: hidden = relu(comb@w1^T+b1); out2 = comb + hidden@w2^T + b2
    k_gemm<true,false,false,true><<<dim3(DFF/64, N_NODES/64),256,0,stream>>>(
        bB, w1, b1, nullptr, bH, N_NODES, DFF, DIM);
    k_gemm<false,false,true,true><<<dim3(DIM/64, N_NODES/64),256,0,stream>>>(
        bH, w2, b2, bB, bC, N_NODES, DIM, DFF);
    // out3 = BN3(out2)
    hipMemsetAsync(sumb, 0, 2*DIM*sizeof(float), stream);
    k_bn_stats<false><<<128,256,0,stream>>>(bC, nullptr, sumb, sqb);
    k_bn_apply<false,false><<<N_NODES,256,0,stream>>>(bC, nullptr, sumb, sqb,
        n3_w + l*DIM, n3_b + l*DIM, bB);
    // H += relu(BN_outer(out3))
    hipMemsetAsync(sumb, 0, 2*DIM*sizeof(float), stream);
    k_bn_stats<false><<<128,256,0,stream>>>(bB, nullptr, sumb, sqb);
    k_bn_apply<false,true><<<N_NODES,256,0,stream>>>(bB, nullptr, sumb, sqb,
        bn_w + l*DIM, bn_b + l*DIM, H);
  }

  // pooled mean per graph + output head
  hipMemsetAsync(pooled, 0, BGRAPH*DIM*sizeof(float), stream);
  k_pool<<<dim3(BGRAPH, NPG/64),256,0,stream>>>(H, pooled);
  k_out<<<1,512,0,stream>>>(pooled, w_out, b_out, (float*)d_out);
}

// Round 3
// 442.097 us; speedup vs baseline: 3.5326x; 3.5326x over previous
//
#include <hip/hip_runtime.h>
#include <hip/hip_bf16.h>

#define N_NODES 8192
#define BGRAPH 8
#define NPG 1024
#define DIM 256
#define NH 8
#define DHEAD 32
#define NLAYERS 2
#define INC 128
#define OUTD 64
#define NEDGE 262144
#define DFF 512
#define EPS 1e-5f

typedef __attribute__((ext_vector_type(4))) float f32x4;
typedef __attribute__((ext_vector_type(8))) short s16x8;

__device__ __forceinline__ float b2f(ushort u){
  unsigned v = ((unsigned)u) << 16;
  return __builtin_bit_cast(float, v);
}
__device__ __forceinline__ ushort f2b(float f){
  unsigned u = __builtin_bit_cast(unsigned, f);
  u += 0x7fffu + ((u >> 16) & 1u);
  return (ushort)(u >> 16);
}
// async global->LDS, 16B per lane; lds base must be wave-uniform (HW adds lane*16)
__device__ __forceinline__ void gload16(const void* g, void* l){
  __builtin_amdgcn_global_load_lds(
    (const __attribute__((address_space(1))) void*)g,
    (__attribute__((address_space(3))) void*)l,
    16, 0, 0);
}

// ---------------------------------------------------------------------------
// Graph setup
// ---------------------------------------------------------------------------
__global__ void k_count_deg(const int* __restrict__ dst, int* __restrict__ deg){
  int i = blockIdx.x*blockDim.x + threadIdx.x;
  int stride = gridDim.x*blockDim.x;
  for(; i<NEDGE; i+=stride) atomicAdd(&deg[dst[i]], 1);
}
__global__ void k_inv_deg(const int* __restrict__ deg, float* __restrict__ inv_deg){
  int i = blockIdx.x*blockDim.x + threadIdx.x;
  if(i<N_NODES){ int d=deg[i]; inv_deg[i] = 1.0f/(float)(d>0?d:1); }
}
__global__ void k_scan(const int* __restrict__ deg, int* __restrict__ offs){
  __shared__ int s[1024];
  int t = threadIdx.x;
  int base = t*8;
  int loc[8]; int acc=0;
  #pragma unroll
  for(int j=0;j<8;j++){ loc[j]=acc; acc += deg[base+j]; }
  s[t]=acc;
  __syncthreads();
  for(int d=1; d<1024; d<<=1){
    int v = (t>=d)? s[t-d] : 0;
    __syncthreads();
    if(t>=d) s[t]+=v;
    __syncthreads();
  }
  int pre = (t>0)? s[t-1] : 0;
  #pragma unroll
  for(int j=0;j<8;j++) offs[base+j] = pre + loc[j];
  if(t==1023) offs[N_NODES] = s[1023];
}
__global__ void k_fill_csr(const int* __restrict__ src, const int* __restrict__ dst,
                           const int* __restrict__ offs, int* __restrict__ cursor,
                           int* __restrict__ csr){
  int i = blockIdx.x*blockDim.x + threadIdx.x;
  int stride = gridDim.x*blockDim.x;
  for(; i<NEDGE; i+=stride){
    int d = dst[i];
    int p = atomicAdd(&cursor[d], 1);
    csr[offs[d]+p] = src[i];
  }
}

// mean-aggregate neighbors, bf16 in/out, f32 accumulate
__global__ __launch_bounds__(256) void k_aggregate(const ushort* __restrict__ hb,
    const int* __restrict__ offs, const int* __restrict__ csr,
    const float* __restrict__ inv_deg, ushort* __restrict__ aggb){
  __shared__ int sj[256];
  int n = blockIdx.x;
  int d = threadIdx.x;
  int beg=offs[n], end=offs[n+1];
  float s=0.f;
  for(int b0=beg; b0<end; b0+=256){
    int cnt = min(256, end-b0);
    __syncthreads();
    if(d<cnt) sj[d]=csr[b0+d];
    __syncthreads();
    for(int i=0;i<cnt;i++) s += b2f(hb[(size_t)sj[i]*DIM + d]);
  }
  aggb[(size_t)n*DIM + d] = f2b(s * inv_deg[n]);
}

// ---------------------------------------------------------------------------
// bf16 MFMA GEMM: C[M,Nc] = A[M,K] @ W[Nc,K]^T (+bias)(+resid)(+C)(relu)
// 128x64 tile, BK=64, 256 thr = 4 waves (2x2), each wave 64x32 (4x2 frags)
// LDS XOR-swizzled (chunk ^= row&7), staged via global_load_lds w=16
// ---------------------------------------------------------------------------
template<bool RELU, bool ACC, bool RESID, bool BIAS, bool WF32, bool WBF>
__global__ __launch_bounds__(256) void k_mm(const ushort* __restrict__ A,
    const ushort* __restrict__ W, const float* __restrict__ bias,
    const float* __restrict__ resid, float* __restrict__ Cf,
    ushort* __restrict__ Cb, int M, int Nc, int K)
{
  __shared__ ushort As[128*64];   // 16KB
  __shared__ ushort Bs[64*64];    // 8KB
  const int tid = threadIdx.x;
  const int lane = tid & 63, wave = tid >> 6;
  const int l15 = lane & 15, l4 = lane >> 4;
  const int bm = blockIdx.y*128, bn = blockIdx.x*64;
  const int wr = wave >> 1, wc = wave & 1;
  f32x4 acc[4][2] = {};

  for(int kt=0; kt<K; kt+=64){
    __syncthreads();
    // stage A: 1024 x 16B chunks (row = chunk>>3, q = chunk&7, swizzled source)
    #pragma unroll
    for(int it=0; it<4; ++it){
      int c = (wave*4+it)*64 + lane;
      int row = c >> 3, q = c & 7;
      int qs = q ^ (row & 7);
      const ushort* g = A + (size_t)(bm+row)*K + kt + qs*8;
      gload16(g, (char*)As + (wave*4+it)*1024);
    }
    // stage B: 512 x 16B chunks
    #pragma unroll
    for(int it=0; it<2; ++it){
      int c = (wave*2+it)*64 + lane;
      int row = c >> 3, q = c & 7;
      int qs = q ^ (row & 7);
      const ushort* g = W + (size_t)(bn+row)*K + kt + qs*8;
      gload16(g, (char*)Bs + (wave*2+it)*1024);
    }
    __syncthreads();
    #pragma unroll
    for(int kk=0; kk<2; ++kk){
      s16x8 af[4], bfr[2];
      #pragma unroll
      for(int mi=0; mi<4; ++mi){
        int row = wr*64 + mi*16 + l15;
        int col = (kk*64 + l4*16) ^ ((row & 7) << 4);
        af[mi] = *(const s16x8*)((const char*)As + row*128 + col);
      }
      #pragma unroll
      for(int nj=0; nj<2; ++nj){
        int row = wc*32 + nj*16 + l15;
        int col = (kk*64 + l4*16) ^ ((row & 7) << 4);
        bfr[nj] = *(const s16x8*)((const char*)Bs + row*128 + col);
      }
      #pragma unroll
      for(int mi=0; mi<4; ++mi)
        #pragma unroll
        for(int nj=0; nj<2; ++nj)
          acc[mi][nj] = __builtin_amdgcn_mfma_f32_16x16x32_bf16(af[mi], bfr[nj], acc[mi][nj], 0,0,0);
    }
  }
  // epilogue: D layout col=lane&15, row=(lane>>4)*4+r
  #pragma unroll
  for(int mi=0; mi<4; ++mi){
    #pragma unroll
    for(int nj=0; nj<2; ++nj){
      int col = bn + wc*32 + nj*16 + l15;
      float bv = BIAS ? bias[col] : 0.f;
      #pragma unroll
      for(int r=0; r<4; ++r){
        int row = bm + wr*64 + mi*16 + l4*4 + r;
        size_t off = (size_t)row*Nc + col;
        float v = acc[mi][nj][r] + bv;
        if(RESID) v += resid[off];
        if(ACC)   v += Cf[off];
        if(RELU)  v = fmaxf(v, 0.f);
        if(WF32)  Cf[off] = v;
        if(WBF)   Cb[off] = f2b(v);
      }
    }
  }
}

// ---------------------------------------------------------------------------
// MFMA flash attention. Block=256 thr=4 waves, each wave 16 queries of one
// (graph,head); grid = 8*8*16 = 1024. Keys staged 64 at a time:
//  - K rows PERMUTED in LDS so the two swapped-QK^T score tiles give P in
//    exactly the 16x16x32 A-fragment order for PV (no cross-lane shuffles)
//  - V stored transposed [d][key], XOR-swizzled -> PV B-frag = 1 ds_read_b128
// ---------------------------------------------------------------------------
__global__ __launch_bounds__(256) void k_attn(const ushort* __restrict__ qkv,
                                              ushort* __restrict__ attnO)
{
  __shared__ ushort Ks[64*32];   // [64 rows][32 d] permuted+swizzled, 4KB
  __shared__ ushort Vt[32*64];   // [32 d][64 keys] swizzled, 4KB
  const int tid = threadIdx.x, lane = tid & 63, wave = tid >> 6;
  const int l15 = lane & 15, g = lane >> 4;
  int bid = blockIdx.x;
  int qc = bid & 15;
  int h  = (bid >> 4) & 7;
  int bg = bid >> 7;
  const int nb = bg*NPG + qc*64 + wave*16;
  const int kb = bg*NPG;

  // Q frag (B operand): lane: q=l15, d = 8*g..+8 ; fold in 1/sqrt(32)
  s16x8 qf = *(const s16x8*)(qkv + (size_t)(nb + l15)*768 + h*32 + g*8);
  {
    const float scale = 0.17677669529663687f;
    #pragma unroll
    for(int i=0;i<8;i++) qf[i] = (short)f2b(b2f((ushort)qf[i]) * scale);
  }
  f32x4 o0 = {0.f,0.f,0.f,0.f}, o1 = {0.f,0.f,0.f,0.f};
  float mrun = -1e30f, lrun = 0.f;

  for(int st=0; st<16; ++st){
    __syncthreads();
    { // stage K: 256 x 16B chunks, permuted rows + swizzled cols
      int rho = tid >> 2, q = tid & 3;
      int grp = rho >> 5, r32 = rho & 31;
      int tt = r32 >> 4, wi = r32 & 15;
      int j = grp*32 + (wi >> 2)*8 + tt*4 + (wi & 3);
      int qs = q ^ ((rho >> 1) & 3);
      const ushort* gp = qkv + (size_t)(kb + st*64 + j)*768 + 256 + h*32 + qs*8;
      gload16(gp, (char*)Ks + wave*1024);
    }
    { // stage V transposed: lane = key, wave = d-octet
      int j = lane;
      s16x8 vv = *(const s16x8*)(qkv + (size_t)(kb + st*64 + j)*768 + 512 + h*32 + wave*8);
      #pragma unroll
      for(int i=0;i<8;i++){
        int d = wave*8 + i;
        Vt[d*64 + (j ^ (i<<3))] = (ushort)vv[i];
      }
    }
    __syncthreads();
    #pragma unroll
    for(int g32=0; g32<2; ++g32){
      // swapped QK^T: two 16-key tiles
      int rho0 = g32*32 + l15;
      int rho1 = g32*32 + 16 + l15;
      s16x8 k0 = *(const s16x8*)((const char*)Ks + rho0*64 + ((g*16) ^ (((rho0>>1)&3)<<4)));
      s16x8 k1 = *(const s16x8*)((const char*)Ks + rho1*64 + ((g*16) ^ (((rho1>>1)&3)<<4)));
      f32x4 z = {0.f,0.f,0.f,0.f};
      f32x4 s0 = __builtin_amdgcn_mfma_f32_16x16x32_bf16(k0, qf, z, 0,0,0);
      f32x4 s1 = __builtin_amdgcn_mfma_f32_16x16x32_bf16(k1, qf, z, 0,0,0);
      // online softmax for query l15 over these 32 keys
      float smax = fmaxf(fmaxf(fmaxf(s0[0],s0[1]),fmaxf(s0[2],s0[3])),
                         fmaxf(fmaxf(s1[0],s1[1]),fmaxf(s1[2],s1[3])));
      smax = fmaxf(smax, __shfl_xor(smax, 16));
      smax = fmaxf(smax, __shfl_xor(smax, 32));
      float mnew = fmaxf(mrun, smax);
      float alpha = __expf(mrun - mnew);
      float p[8];
      float ps = 0.f;
      #pragma unroll
      for(int i=0;i<4;i++){ p[i]   = __expf(s0[i]-mnew); ps += p[i]; }
      #pragma unroll
      for(int i=0;i<4;i++){ p[4+i] = __expf(s1[i]-mnew); ps += p[4+i]; }
      ps += __shfl_xor(ps, 16);
      ps += __shfl_xor(ps, 32);
      lrun = lrun*alpha + ps;
      mrun = mnew;
      // rescale O rows by alpha of query q2=g*4+r (held at lanes with l15==q2)
      #pragma unroll
      for(int r=0;r<4;r++){
        float ar = __shfl(alpha, (lane & 48) | (g*4 + r), 64);
        o0[r] *= ar; o1[r] *= ar;
      }
      // PA: by K-row permutation, p[e] is already A[row=q=l15][k=8g+e]
      s16x8 pa;
      #pragma unroll
      for(int i=0;i<8;i++) pa[i] = (short)f2b(p[i]);
      // V frags: B[k=8g+e][dh=l15(+16)]
      int colb = g32*64 + g*16;
      int d0 = l15, d1 = l15 + 16;
      s16x8 v0 = *(const s16x8*)((const char*)Vt + d0*128 + (colb ^ ((d0&7)<<4)));
      s16x8 v1 = *(const s16x8*)((const char*)Vt + d1*128 + (colb ^ ((d1&7)<<4)));
      o0 = __builtin_amdgcn_mfma_f32_16x16x32_bf16(pa, v0, o0, 0,0,0);
      o1 = __builtin_amdgcn_mfma_f32_16x16x32_bf16(pa, v1, o1, 0,0,0);
    }
  }
  float inv = 1.0f/lrun;
  #pragma unroll
  for(int r=0;r<4;r++){
    int q2 = g*4 + r;
    float ir = __shfl(inv, (lane & 48) | q2, 64);
    size_t nrow = (size_t)(nb + q2)*DIM + h*32;
    attnO[nrow + l15]      = f2b(o0[r]*ir);
    attnO[nrow + 16 + l15] = f2b(o1[r]*ir);
  }
}

// ---------------------------------------------------------------------------
// BatchNorm + elementwise
// ---------------------------------------------------------------------------
template<bool ADD>
__global__ __launch_bounds__(256) void k_bn_stats(const float* __restrict__ x,
    const float* __restrict__ add, float* __restrict__ sumb, float* __restrict__ sqb){
  int d = threadIdx.x;
  int r0 = blockIdx.x*64;
  float s=0.f, q=0.f;
  for(int r=r0; r<r0+64; ++r){
    float v = x[(size_t)r*DIM+d];
    if(ADD) v += add[(size_t)r*DIM+d];
    s += v; q += v*v;
  }
  atomicAdd(&sumb[d], s);
  atomicAdd(&sqb[d], q);
}

template<bool ADD>
__global__ __launch_bounds__(256) void k_bn_apply_f32(const float* __restrict__ x,
    const float* __restrict__ add, const float* __restrict__ sumb,
    const float* __restrict__ sqb, const float* __restrict__ w,
    const float* __restrict__ b, float* __restrict__ out){
  int d = threadIdx.x;
  size_t idx = (size_t)blockIdx.x*DIM + d;
  float m = sumb[d]*(1.0f/N_NODES);
  float v = sqb[d]*(1.0f/N_NODES) - m*m;
  float rs = rsqrtf(v + EPS);
  float val = x[idx];
  if(ADD) val += add[idx];
  out[idx] = (val - m)*rs*w[d] + b[d];
}

__global__ __launch_bounds__(256) void k_bn_apply_relu_add(const float* __restrict__ x,
    const float* __restrict__ sumb, const float* __restrict__ sqb,
    const float* __restrict__ w, const float* __restrict__ b,
    float* __restrict__ H, ushort* __restrict__ Hb){
  int d = threadIdx.x;
  size_t idx = (size_t)blockIdx.x*DIM + d;
  float m = sumb[d]*(1.0f/N_NODES);
  float v = sqb[d]*(1.0f/N_NODES) - m*m;
  float rs = rsqrtf(v + EPS);
  float y = (x[idx] - m)*rs*w[d] + b[d];
  float h = H[idx] + fmaxf(y, 0.f);
  H[idx] = h;
  Hb[idx] = f2b(h);
}

__global__ void k_add_cast(float* __restrict__ a, const float* __restrict__ b,
                           ushort* __restrict__ ab){
  size_t i = (size_t)blockIdx.x*256 + threadIdx.x;
  float v = a[i] + b[i];
  a[i] = v;
  ab[i] = f2b(v);
}

// cast x + all weights (contiguous dst region) f32 -> bf16
// segment sizes: x 1048576 | w_in 32768 | wl 131072 | wr 131072 |
//                iw 393216 | ow 131072 | w1 262144 | w2 262144
#define CX  1048576
#define CWI (CX+32768)
#define CWL (CWI+131072)
#define CWR (CWL+131072)
#define CIW (CWR+393216)
#define COW (CIW+131072)
#define CW1 (COW+262144)
#define CW2 (CW1+262144)   // total 2392064
__global__ void k_cast_all(const float* __restrict__ x, const float* __restrict__ w_in,
    const float* __restrict__ wl, const float* __restrict__ wr,
    const float* __restrict__ iw, const float* __restrict__ ow,
    const float* __restrict__ w1, const float* __restrict__ w2,
    ushort* __restrict__ dst){
  int i = blockIdx.x*256 + threadIdx.x;
  const float* s; int off;
  if(i < CX)       { s=x;    off=0;   }
  else if(i < CWI) { s=w_in; off=CX;  }
  else if(i < CWL) { s=wl;   off=CWI; }
  else if(i < CWR) { s=wr;   off=CWL; }
  else if(i < CIW) { s=iw;   off=CWR; }
  else if(i < COW) { s=ow;   off=CIW; }
  else if(i < CW1) { s=w1;   off=COW; }
  else             { s=w2;   off=CW1; }
  dst[i] = f2b(s[i-off]);
}

// ---------------------------------------------------------------------------
// Pooling + head
// ---------------------------------------------------------------------------
__global__ void k_pool(const float* __restrict__ h, float* __restrict__ pooled){
  int b = blockIdx.x, c = blockIdx.y, d = threadIdx.x;
  int r0 = c*64;
  float s=0.f;
  for(int i=0;i<64;i++) s += h[(size_t)(b*NPG + r0 + i)*DIM + d];
  atomicAdd(&pooled[b*DIM+d], s*(1.0f/NPG));
}
__global__ void k_out(const float* __restrict__ pooled, const float* __restrict__ w_out,
                      const float* __restrict__ b_out, float* __restrict__ out){
  int t = threadIdx.x;
  if(t >= BGRAPH*OUTD) return;
  int b = t/OUTD, oc = t%OUTD;
  float s = b_out[oc];
  for(int k=0;k<DIM;k++) s += pooled[b*DIM+k]*w_out[oc*DIM+k];
  out[t] = s;
}

// ---------------------------------------------------------------------------
// Orchestration
// ---------------------------------------------------------------------------
extern "C" void kernel_launch(void* const* d_in, const int* in_sizes, int n_in,
                              void* d_out, int out_size, void* d_ws, size_t ws_size,
                              hipStream_t stream) {
  const float* x       = (const float*)d_in[0];
  const int*   edge    = (const int*)d_in[1];
  const float* w_in    = (const float*)d_in[3];
  const float* b_in    = (const float*)d_in[4];
  const float* sage_wl = (const float*)d_in[5];
  const float* sage_bl = (const float*)d_in[6];
  const float* sage_wr = (const float*)d_in[7];
  const float* attn_iw = (const float*)d_in[8];
  const float* attn_ib = (const float*)d_in[9];
  const float* attn_ow = (const float*)d_in[10];
  const float* attn_ob = (const float*)d_in[11];
  const float* n1_w = (const float*)d_in[12];
  const float* n1_b = (const float*)d_in[13];
  const float* n2_w = (const float*)d_in[14];
  const float* n2_b = (const float*)d_in[15];
  const float* n3_w = (const float*)d_in[16];
  const float* n3_b = (const float*)d_in[17];
  const float* mlp_w1 = (const float*)d_in[18];
  const float* mlp_b1 = (const float*)d_in[19];
  const float* mlp_w2 = (const float*)d_in[20];
  const float* mlp_b2 = (const float*)d_in[21];
  const float* bn_w = (const float*)d_in[22];
  const float* bn_b = (const float*)d_in[23];
  const float* w_out = (const float*)d_in[24];
  const float* b_out = (const float*)d_in[25];

  const size_t ND = (size_t)N_NODES*DIM;        // 2,097,152
  float* ws   = (float*)d_ws;
  float* H    = ws;            // f32
  float* locC = ws + ND;       // f32
  float* globC= ws + 2*ND;     // f32
  ushort* wsb = (ushort*)(ws + 3*ND);
  ushort* Hb     = wsb;
  ushort* aggb   = wsb + ND;
  ushort* qkvb   = wsb + 2*ND;     // 3*ND
  ushort* attnOb = wsb + 5*ND;
  ushort* combb  = wsb + 6*ND;
  ushort* hidb   = wsb + 7*ND;     // 2*ND
  ushort* castb  = wsb + 9*ND;     // x + weights, CW2 elems
  ushort* xb     = castb;
  ushort* w_in_b = castb + CX;
  ushort* wl_b   = castb + CWI;
  ushort* wr_b   = castb + CWL;
  ushort* iw_b   = castb + CWR;
  ushort* ow_b   = castb + CIW;
  ushort* w1_b   = castb + COW;
  ushort* w2_b   = castb + CW1;
  float* mf      = (float*)(castb + CW2);
  float* inv_deg = mf;
  float* sumb    = mf + 8192;
  float* sqb     = sumb + 256;
  float* pooled  = sqb + 256;
  int* ip     = (int*)(pooled + 2048);
  int* deg    = ip;
  int* cursor = ip + N_NODES;
  int* offs   = ip + 2*N_NODES;
  int* csr    = ip + 2*N_NODES + N_NODES + 8;

  const int* esrc = edge;
  const int* edst = edge + NEDGE;

  // graph structure
  hipMemsetAsync(deg, 0, 2*N_NODES*sizeof(int), stream);   // deg + cursor
  k_count_deg<<<512,256,0,stream>>>(edst, deg);
  k_inv_deg<<<(N_NODES+255)/256,256,0,stream>>>(deg, inv_deg);
  k_scan<<<1,1024,0,stream>>>(deg, offs);
  k_fill_csr<<<512,256,0,stream>>>(esrc, edst, offs, cursor, csr);

  // casts
  k_cast_all<<<CW2/256,256,0,stream>>>(x, w_in, sage_wl, sage_wr, attn_iw,
      attn_ow, mlp_w1, mlp_w2, castb);

  // in_proj: H(f32)+Hb(bf16) = x @ w_in^T + b_in
  k_mm<false,false,false,true,true,true><<<dim3(4,64),256,0,stream>>>(
      xb, w_in_b, b_in, nullptr, H, Hb, N_NODES, DIM, INC);

  for(int l=0; l<NLAYERS; ++l){
    const ushort* wlb = wl_b + (size_t)l*65536;
    const ushort* wrb = wr_b + (size_t)l*65536;
    const ushort* iwb = iw_b + (size_t)l*196608;
    const ushort* owb = ow_b + (size_t)l*65536;
    const ushort* w1b = w1_b + (size_t)l*131072;
    const ushort* w2b = w2_b + (size_t)l*131072;

    // SAGE
    k_aggregate<<<N_NODES,256,0,stream>>>(Hb, offs, csr, inv_deg, aggb);
    k_mm<false,false,false,true,true,false><<<dim3(4,64),256,0,stream>>>(
        aggb, wlb, sage_bl + l*DIM, nullptr, locC, nullptr, N_NODES, DIM, DIM);
    k_mm<false,true,false,false,true,false><<<dim3(4,64),256,0,stream>>>(
        Hb, wrb, nullptr, nullptr, locC, nullptr, N_NODES, DIM, DIM);
    hipMemsetAsync(sumb, 0, 512*sizeof(float), stream);
    k_bn_stats<true><<<128,256,0,stream>>>(locC, H, sumb, sqb);
    k_bn_apply_f32<true><<<N_NODES,256,0,stream>>>(locC, H, sumb, sqb,
        n1_w + l*DIM, n1_b + l*DIM, locC);

    // attention
    k_mm<false,false,false,true,false,true><<<dim3(12,64),256,0,stream>>>(
        Hb, iwb, attn_ib + l*3*DIM, nullptr, nullptr, qkvb, N_NODES, 3*DIM, DIM);
    k_attn<<<1024,256,0,stream>>>(qkvb, attnOb);
    k_mm<false,false,false,true,true,false><<<dim3(4,64),256,0,stream>>>(
        attnOb, owb, attn_ob + l*DIM, nullptr, globC, nullptr, N_NODES, DIM, DIM);
    hipMemsetAsync(sumb, 0, 512*sizeof(float), stream);
    k_bn_stats<true><<<128,256,0,stream>>>(globC, H, sumb, sqb);
    k_bn_apply_f32<true><<<N_NODES,256,0,stream>>>(globC, H, sumb, sqb,
        n2_w + l*DIM, n2_b + l*DIM, globC);

    // comb = loc + glob (f32 in locC, bf16 in combb)
    k_add_cast<<<N_NODES,256,0,stream>>>(locC, globC, combb);
    // MLP
    k_mm<true,false,false,true,false,true><<<dim3(8,64),256,0,stream>>>(
        combb, w1b, mlp_b1 + l*DFF, nullptr, nullptr, hidb, N_NODES, DFF, DIM);
    k_mm<false,false,true,true,true,false><<<dim3(4,64),256,0,stream>>>(
        hidb, w2b, mlp_b2 + l*DIM, locC, globC, nullptr, N_NODES, DIM, DFF);
    // BN3
    hipMemsetAsync(sumb, 0, 512*sizeof(float), stream);
    k_bn_stats<false><<<128,256,0,stream>>>(globC, nullptr, sumb, sqb);
    k_bn_apply_f32<false><<<N_NODES,256,0,stream>>>(globC, nullptr, sumb, sqb,
        n3_w + l*DIM, n3_b + l*DIM, locC);
    // outer BN + relu + residual into H/Hb
    hipMemsetAsync(sumb, 0, 512*sizeof(float), stream);
    k_bn_stats<false><<<128,256,0,stream>>>(locC, nullptr, sumb, sqb);
    k_bn_apply_relu_add<<<N_NODES,256,0,stream>>>(locC, sumb, sqb,
        bn_w + l*DIM, bn_b + l*DIM, H, Hb);
  }

  hipMemsetAsync(pooled, 0, BGRAPH*DIM*sizeof(float), stream);
  k_pool<<<dim3(BGRAPH, NPG/64),256,0,stream>>>(H, pooled);
  k_out<<<1,512,0,stream>>>(pooled, w_out, b_out, (float*)d_out);
}

// Round 4
// 330.176 us; speedup vs baseline: 4.7300x; 1.3390x over previous
//
#include <hip/hip_runtime.h>
#include <hip/hip_bf16.h>

#define N_NODES 8192
#define BGRAPH 8
#define NPG 1024
#define DIM 256
#define NH 8
#define DHEAD 32
#define NLAYERS 2
#define INC 128
#define OUTD 64
#define NEDGE 262144
#define DFF 512
#define EPS 1e-5f

typedef __attribute__((ext_vector_type(4))) float f32x4;
typedef __attribute__((ext_vector_type(8))) short s16x8;

__device__ __forceinline__ float b2f(ushort u){
  unsigned v = ((unsigned)u) << 16;
  return __builtin_bit_cast(float, v);
}
__device__ __forceinline__ ushort f2b(float f){
  unsigned u = __builtin_bit_cast(unsigned, f);
  u += 0x7fffu + ((u >> 16) & 1u);
  return (ushort)(u >> 16);
}
// async global->LDS, 16B per lane; lds base must be wave-uniform (HW adds lane*16)
__device__ __forceinline__ void gload16(const void* g, void* l){
  __builtin_amdgcn_global_load_lds(
    (const __attribute__((address_space(1))) void*)g,
    (__attribute__((address_space(3))) void*)l,
    16, 0, 0);
}

// ---------------------------------------------------------------------------
// Graph setup
// ---------------------------------------------------------------------------
__global__ void k_count_deg(const int* __restrict__ dst, int* __restrict__ deg){
  int i = blockIdx.x*blockDim.x + threadIdx.x;
  int stride = gridDim.x*blockDim.x;
  for(; i<NEDGE; i+=stride) atomicAdd(&deg[dst[i]], 1);
}
// scan + inv_deg in one kernel (single block, 1024 threads)
__global__ void k_scan(const int* __restrict__ deg, int* __restrict__ offs,
                       float* __restrict__ inv_deg){
  __shared__ int s[1024];
  int t = threadIdx.x;
  int base = t*8;
  int loc[8]; int acc=0;
  #pragma unroll
  for(int j=0;j<8;j++){
    int dv = deg[base+j];
    inv_deg[base+j] = 1.0f/(float)(dv>0?dv:1);
    loc[j]=acc; acc += dv;
  }
  s[t]=acc;
  __syncthreads();
  for(int d=1; d<1024; d<<=1){
    int v = (t>=d)? s[t-d] : 0;
    __syncthreads();
    if(t>=d) s[t]+=v;
    __syncthreads();
  }
  int pre = (t>0)? s[t-1] : 0;
  #pragma unroll
  for(int j=0;j<8;j++) offs[base+j] = pre + loc[j];
  if(t==1023) offs[N_NODES] = s[1023];
}
__global__ void k_fill_csr(const int* __restrict__ src, const int* __restrict__ dst,
                           const int* __restrict__ offs, int* __restrict__ cursor,
                           int* __restrict__ csr){
  int i = blockIdx.x*blockDim.x + threadIdx.x;
  int stride = gridDim.x*blockDim.x;
  for(; i<NEDGE; i+=stride){
    int d = dst[i];
    int p = atomicAdd(&cursor[d], 1);
    csr[offs[d]+p] = src[i];
  }
}

// mean-aggregate neighbors; reads H from right half of wide buffer [N][512],
// writes agg into left half
__global__ __launch_bounds__(256) void k_aggregate(ushort* __restrict__ hwb,
    const int* __restrict__ offs, const int* __restrict__ csr,
    const float* __restrict__ inv_deg){
  __shared__ int sj[256];
  int n = blockIdx.x;
  int d = threadIdx.x;
  int beg=offs[n], end=offs[n+1];
  float s=0.f;
  for(int b0=beg; b0<end; b0+=256){
    int cnt = min(256, end-b0);
    __syncthreads();
    if(d<cnt) sj[d]=csr[b0+d];
    __syncthreads();
    for(int i=0;i<cnt;i++) s += b2f(hwb[(size_t)sj[i]*512 + 256 + d]);
  }
  hwb[(size_t)n*512 + d] = f2b(s * inv_deg[n]);
}

// ---------------------------------------------------------------------------
// bf16 MFMA GEMM: C[M,Nc] = A[M,K] @ W[Nc,K]^T (+bias)(+resid) -> f32/bf16
// optional fused BN stats (per-column sum/sumsq atomics). lda-aware.
// 128x64 tile, BK=64, 256 thr = 4 waves (2x2)
// ---------------------------------------------------------------------------
template<bool RELU, bool RESID, bool BIAS, bool WF32, bool WBF, bool STATS>
__global__ __launch_bounds__(256) void k_mm(const ushort* __restrict__ A,
    const ushort* __restrict__ W, const float* __restrict__ bias,
    const float* __restrict__ resid, float* __restrict__ Cf,
    ushort* __restrict__ Cb, float* __restrict__ gS, float* __restrict__ gQ,
    int M, int Nc, int K, int lda, int ldcb)
{
  __shared__ ushort As[128*64];   // 16KB
  __shared__ ushort Bs[64*64];    // 8KB
  __shared__ float sredS[64];
  __shared__ float sredQ[64];
  const int tid = threadIdx.x;
  const int lane = tid & 63, wave = tid >> 6;
  const int l15 = lane & 15, l4 = lane >> 4;
  const int bm = blockIdx.y*128, bn = blockIdx.x*64;
  const int wr = wave >> 1, wc = wave & 1;
  f32x4 acc[4][2] = {};

  for(int kt=0; kt<K; kt+=64){
    __syncthreads();
    #pragma unroll
    for(int it=0; it<4; ++it){
      int c = (wave*4+it)*64 + lane;
      int row = c >> 3, q = c & 7;
      int qs = q ^ (row & 7);
      const ushort* g = A + (size_t)(bm+row)*lda + kt + qs*8;
      gload16(g, (char*)As + (wave*4+it)*1024);
    }
    #pragma unroll
    for(int it=0; it<2; ++it){
      int c = (wave*2+it)*64 + lane;
      int row = c >> 3, q = c & 7;
      int qs = q ^ (row & 7);
      const ushort* g = W + (size_t)(bn+row)*K + kt + qs*8;
      gload16(g, (char*)Bs + (wave*2+it)*1024);
    }
    __syncthreads();
    #pragma unroll
    for(int kk=0; kk<2; ++kk){
      s16x8 af[4], bfr[2];
      #pragma unroll
      for(int mi=0; mi<4; ++mi){
        int row = wr*64 + mi*16 + l15;
        int col = (kk*64 + l4*16) ^ ((row & 7) << 4);
        af[mi] = *(const s16x8*)((const char*)As + row*128 + col);
      }
      #pragma unroll
      for(int nj=0; nj<2; ++nj){
        int row = wc*32 + nj*16 + l15;
        int col = (kk*64 + l4*16) ^ ((row & 7) << 4);
        bfr[nj] = *(const s16x8*)((const char*)Bs + row*128 + col);
      }
      #pragma unroll
      for(int mi=0; mi<4; ++mi)
        #pragma unroll
        for(int nj=0; nj<2; ++nj)
          acc[mi][nj] = __builtin_amdgcn_mfma_f32_16x16x32_bf16(af[mi], bfr[nj], acc[mi][nj], 0,0,0);
    }
  }
  float sloc[2] = {0.f,0.f}, qloc[2] = {0.f,0.f};
  #pragma unroll
  for(int mi=0; mi<4; ++mi){
    #pragma unroll
    for(int nj=0; nj<2; ++nj){
      int col = bn + wc*32 + nj*16 + l15;
      float bv = BIAS ? bias[col] : 0.f;
      #pragma unroll
      for(int r=0; r<4; ++r){
        int row = bm + wr*64 + mi*16 + l4*4 + r;
        size_t off = (size_t)row*Nc + col;
        float v = acc[mi][nj][r] + bv;
        if(RESID) v += resid[off];
        if(RELU)  v = fmaxf(v, 0.f);
        if(WF32)  Cf[off] = v;
        if(WBF)   Cb[(size_t)row*ldcb + col] = f2b(v);
        if(STATS){ sloc[nj] += v; qloc[nj] += v*v; }
      }
    }
  }
  if(STATS){
    if(tid < 64){ sredS[tid]=0.f; sredQ[tid]=0.f; }
    __syncthreads();
    int c0 = wc*32 + l15;
    atomicAdd(&sredS[c0],    sloc[0]); atomicAdd(&sredQ[c0],    qloc[0]);
    atomicAdd(&sredS[c0+16], sloc[1]); atomicAdd(&sredQ[c0+16], qloc[1]);
    __syncthreads();
    if(tid < 64){
      atomicAdd(&gS[bn+tid], sredS[tid]);
      atomicAdd(&gQ[bn+tid], sredQ[tid]);
    }
  }
}

// ---------------------------------------------------------------------------
// MFMA flash attention (unchanged, verified round 3)
// ---------------------------------------------------------------------------
__global__ __launch_bounds__(256) void k_attn(const ushort* __restrict__ qkv,
                                              ushort* __restrict__ attnO)
{
  __shared__ ushort Ks[64*32];
  __shared__ ushort Vt[32*64];
  const int tid = threadIdx.x, lane = tid & 63, wave = tid >> 6;
  const int l15 = lane & 15, g = lane >> 4;
  int bid = blockIdx.x;
  int qc = bid & 15;
  int h  = (bid >> 4) & 7;
  int bg = bid >> 7;
  const int nb = bg*NPG + qc*64 + wave*16;
  const int kb = bg*NPG;

  s16x8 qf = *(const s16x8*)(qkv + (size_t)(nb + l15)*768 + h*32 + g*8);
  {
    const float scale = 0.17677669529663687f;
    #pragma unroll
    for(int i=0;i<8;i++) qf[i] = (short)f2b(b2f((ushort)qf[i]) * scale);
  }
  f32x4 o0 = {0.f,0.f,0.f,0.f}, o1 = {0.f,0.f,0.f,0.f};
  float mrun = -1e30f, lrun = 0.f;

  for(int st=0; st<16; ++st){
    __syncthreads();
    {
      int rho = tid >> 2, q = tid & 3;
      int grp = rho >> 5, r32 = rho & 31;
      int tt = r32 >> 4, wi = r32 & 15;
      int j = grp*32 + (wi >> 2)*8 + tt*4 + (wi & 3);
      int qs = q ^ ((rho >> 1) & 3);
      const ushort* gp = qkv + (size_t)(kb + st*64 + j)*768 + 256 + h*32 + qs*8;
      gload16(gp, (char*)Ks + wave*1024);
    }
    {
      int j = lane;
      s16x8 vv = *(const s16x8*)(qkv + (size_t)(kb + st*64 + j)*768 + 512 + h*32 + wave*8);
      #pragma unroll
      for(int i=0;i<8;i++){
        int d = wave*8 + i;
        Vt[d*64 + (j ^ (i<<3))] = (ushort)vv[i];
      }
    }
    __syncthreads();
    #pragma unroll
    for(int g32=0; g32<2; ++g32){
      int rho0 = g32*32 + l15;
      int rho1 = g32*32 + 16 + l15;
      s16x8 k0 = *(const s16x8*)((const char*)Ks + rho0*64 + ((g*16) ^ (((rho0>>1)&3)<<4)));
      s16x8 k1 = *(const s16x8*)((const char*)Ks + rho1*64 + ((g*16) ^ (((rho1>>1)&3)<<4)));
      f32x4 z = {0.f,0.f,0.f,0.f};
      f32x4 s0 = __builtin_amdgcn_mfma_f32_16x16x32_bf16(k0, qf, z, 0,0,0);
      f32x4 s1 = __builtin_amdgcn_mfma_f32_16x16x32_bf16(k1, qf, z, 0,0,0);
      float smax = fmaxf(fmaxf(fmaxf(s0[0],s0[1]),fmaxf(s0[2],s0[3])),
                         fmaxf(fmaxf(s1[0],s1[1]),fmaxf(s1[2],s1[3])));
      smax = fmaxf(smax, __shfl_xor(smax, 16));
      smax = fmaxf(smax, __shfl_xor(smax, 32));
      float mnew = fmaxf(mrun, smax);
      float alpha = __expf(mrun - mnew);
      float p[8];
      float ps = 0.f;
      #pragma unroll
      for(int i=0;i<4;i++){ p[i]   = __expf(s0[i]-mnew); ps += p[i]; }
      #pragma unroll
      for(int i=0;i<4;i++){ p[4+i] = __expf(s1[i]-mnew); ps += p[4+i]; }
      ps += __shfl_xor(ps, 16);
      ps += __shfl_xor(ps, 32);
      lrun = lrun*alpha + ps;
      mrun = mnew;
      #pragma unroll
      for(int r=0;r<4;r++){
        float ar = __shfl(alpha, (lane & 48) | (g*4 + r), 64);
        o0[r] *= ar; o1[r] *= ar;
      }
      s16x8 pa;
      #pragma unroll
      for(int i=0;i<8;i++) pa[i] = (short)f2b(p[i]);
      int colb = g32*64 + g*16;
      int d0 = l15, d1 = l15 + 16;
      s16x8 v0 = *(const s16x8*)((const char*)Vt + d0*128 + (colb ^ ((d0&7)<<4)));
      s16x8 v1 = *(const s16x8*)((const char*)Vt + d1*128 + (colb ^ ((d1&7)<<4)));
      o0 = __builtin_amdgcn_mfma_f32_16x16x32_bf16(pa, v0, o0, 0,0,0);
      o1 = __builtin_amdgcn_mfma_f32_16x16x32_bf16(pa, v1, o1, 0,0,0);
    }
  }
  float inv = 1.0f/lrun;
  #pragma unroll
  for(int r=0;r<4;r++){
    int q2 = g*4 + r;
    float ir = __shfl(inv, (lane & 48) | q2, 64);
    size_t nrow = (size_t)(nb + q2)*DIM + h*32;
    attnO[nrow + l15]      = f2b(o0[r]*ir);
    attnO[nrow + 16 + l15] = f2b(o1[r]*ir);
  }
}

// ---------------------------------------------------------------------------
// Fused BN applies. slot layout per layer: [s1|q1|s2|q2|s3|q3] x 256 floats
// ---------------------------------------------------------------------------
__global__ __launch_bounds__(256) void k_apply12(const float* __restrict__ locC,
    const float* __restrict__ globC, const float* __restrict__ slot,
    const float* __restrict__ n1w, const float* __restrict__ n1b,
    const float* __restrict__ n2w, const float* __restrict__ n2b,
    float* __restrict__ combF, ushort* __restrict__ combB){
  int d = threadIdx.x;
  size_t i = (size_t)blockIdx.x*DIM + d;
  const float invn = 1.0f/N_NODES;
  float m1 = slot[d]*invn,     v1 = slot[256+d]*invn - m1*m1;
  float m2 = slot[512+d]*invn, v2 = slot[768+d]*invn - m2*m2;
  float rs1 = rsqrtf(v1+EPS), rs2 = rsqrtf(v2+EPS);
  float y1 = (locC[i]-m1)*rs1*n1w[d] + n1b[d];
  float y2 = (globC[i]-m2)*rs2*n2w[d] + n2b[d];
  float c = y1 + y2;
  combF[i] = c;
  combB[i] = f2b(c);
}

// BN3 + outer BN + relu + residual (closed form: mean(BN3)=b3, var(BN3)=(rs*w3)^2*var)
__global__ __launch_bounds__(256) void k_apply3o(const float* __restrict__ x,
    const float* __restrict__ slot, const float* __restrict__ n3w,
    const float* __restrict__ n3b, const float* __restrict__ bw,
    const float* __restrict__ bb, float* __restrict__ H,
    ushort* __restrict__ hwbR){
  int d = threadIdx.x;
  size_t i = (size_t)blockIdx.x*DIM + d;
  const float invn = 1.0f/N_NODES;
  float m   = slot[1024+d]*invn;
  float var = slot[1280+d]*invn - m*m;
  float rs  = rsqrtf(var+EPS);
  float gch = rs*n3w[d];
  float rso = rsqrtf(gch*gch*var + EPS);
  float yo = (x[i]-m)*gch*rso*bw[d] + bb[d];
  float h = H[i] + fmaxf(yo, 0.f);
  H[i] = h;
  hwbR[(size_t)blockIdx.x*512 + d] = f2b(h);
}

// ---------------------------------------------------------------------------
// cast x + weights f32 -> bf16 ; SAGE weights fused as [wl|wr] along K
// ---------------------------------------------------------------------------
#define CX  1048576
#define CWI (CX+32768)
#define CSW (CWI+262144)
#define CIW (CSW+393216)
#define COW (CIW+131072)
#define CW1 (COW+262144)
#define CW2 (CW1+262144)   // total 2392064
__global__ void k_cast_all(const float* __restrict__ x, const float* __restrict__ w_in,
    const float* __restrict__ wl, const float* __restrict__ wr,
    const float* __restrict__ iw, const float* __restrict__ ow,
    const float* __restrict__ w1, const float* __restrict__ w2,
    ushort* __restrict__ dst){
  int i = blockIdx.x*256 + threadIdx.x;
  float val;
  if(i < CX)       val = x[i];
  else if(i < CWI) val = w_in[i-CX];
  else if(i < CSW){
    int j = i - CWI;
    int l = j >> 17, r = (j >> 9) & 255, k = j & 511;
    val = (k < 256) ? wl[(l<<16) + (r<<8) + k] : wr[(l<<16) + (r<<8) + (k-256)];
  }
  else if(i < CIW) val = iw[i-CSW];
  else if(i < COW) val = ow[i-CIW];
  else if(i < CW1) val = w1[i-COW];
  else             val = w2[i-CW1];
  dst[i] = f2b(val);
}

// ---------------------------------------------------------------------------
// Pooling + head
// ---------------------------------------------------------------------------
__global__ void k_pool(const float* __restrict__ h, float* __restrict__ pooled){
  int b = blockIdx.x, c = blockIdx.y, d = threadIdx.x;
  int r0 = c*64;
  float s=0.f;
  for(int i=0;i<64;i++) s += h[(size_t)(b*NPG + r0 + i)*DIM + d];
  atomicAdd(&pooled[b*DIM+d], s*(1.0f/NPG));
}
__global__ void k_out(const float* __restrict__ pooled, const float* __restrict__ w_out,
                      const float* __restrict__ b_out, float* __restrict__ out){
  int t = threadIdx.x;
  if(t >= BGRAPH*OUTD) return;
  int b = t/OUTD, oc = t%OUTD;
  float s = b_out[oc];
  for(int k=0;k<DIM;k++) s += pooled[b*DIM+k]*w_out[oc*DIM+k];
  out[t] = s;
}

// ---------------------------------------------------------------------------
// Orchestration
// ---------------------------------------------------------------------------
extern "C" void kernel_launch(void* const* d_in, const int* in_sizes, int n_in,
                              void* d_out, int out_size, void* d_ws, size_t ws_size,
                              hipStream_t stream) {
  const float* x       = (const float*)d_in[0];
  const int*   edge    = (const int*)d_in[1];
  const float* w_in    = (const float*)d_in[3];
  const float* b_in    = (const float*)d_in[4];
  const float* sage_wl = (const float*)d_in[5];
  const float* sage_bl = (const float*)d_in[6];
  const float* sage_wr = (const float*)d_in[7];
  const float* attn_iw = (const float*)d_in[8];
  const float* attn_ib = (const float*)d_in[9];
  const float* attn_ow = (const float*)d_in[10];
  const float* attn_ob = (const float*)d_in[11];
  const float* n1_w = (const float*)d_in[12];
  const float* n1_b = (const float*)d_in[13];
  const float* n2_w = (const float*)d_in[14];
  const float* n2_b = (const float*)d_in[15];
  const float* n3_w = (const float*)d_in[16];
  const float* n3_b = (const float*)d_in[17];
  const float* mlp_w1 = (const float*)d_in[18];
  const float* mlp_b1 = (const float*)d_in[19];
  const float* mlp_w2 = (const float*)d_in[20];
  const float* mlp_b2 = (const float*)d_in[21];
  const float* bn_w = (const float*)d_in[22];
  const float* bn_b = (const float*)d_in[23];
  const float* w_out = (const float*)d_in[24];
  const float* b_out = (const float*)d_in[25];

  const size_t ND = (size_t)N_NODES*DIM;        // 2,097,152
  float* ws    = (float*)d_ws;
  float* H     = ws;
  float* locC  = ws + ND;
  float* globC = ws + 2*ND;
  float* combF = ws + 3*ND;
  ushort* wsb   = (ushort*)(ws + 4*ND);
  ushort* hwb   = wsb;             // [N][512] : [agg | H] bf16
  ushort* qkvb  = wsb + 2*ND;      // 3*ND
  ushort* attnOb= wsb + 5*ND;
  ushort* combb = wsb + 6*ND;
  ushort* hidb  = wsb + 7*ND;      // [N][512]
  ushort* castb = wsb + 9*ND;
  ushort* xb     = castb;
  ushort* w_in_b = castb + CX;
  ushort* sageWb = castb + CWI;
  ushort* iw_b   = castb + CSW;
  ushort* ow_b   = castb + CIW;
  ushort* w1_b   = castb + COW;
  ushort* w2_b   = castb + CW1;
  float* mf      = (float*)(castb + CW2);
  float* inv_deg = mf;
  float* bnslots = mf + 8192;
  float* pooled  = bnslots + 3072;
  int* deg    = (int*)(pooled + 2048);
  int* cursor = deg + N_NODES;
  int* offs   = cursor + N_NODES;
  int* csr    = offs + N_NODES + 8;

  const int* esrc = edge;
  const int* edst = edge + NEDGE;

  hipMemsetAsync(bnslots, 0, (3072+2048)*sizeof(float) + 2*N_NODES*sizeof(int), stream);

  k_count_deg<<<512,256,0,stream>>>(edst, deg);
  k_scan<<<1,1024,0,stream>>>(deg, offs, inv_deg);
  k_fill_csr<<<512,256,0,stream>>>(esrc, edst, offs, cursor, csr);
  k_cast_all<<<CW2/256,256,0,stream>>>(x, w_in, sage_wl, sage_wr, attn_iw,
      attn_ow, mlp_w1, mlp_w2, castb);

  // in_proj: H(f32) + hwb right half(bf16) = x @ w_in^T + b_in
  k_mm<false,false,true,true,true,false><<<dim3(4,64),256,0,stream>>>(
      xb, w_in_b, b_in, nullptr, H, hwb+256, nullptr, nullptr,
      N_NODES, DIM, INC, INC, 512);

  for(int l=0; l<NLAYERS; ++l){
    const ushort* swb = sageWb + (size_t)l*131072;   // [256][512] = [wl|wr]
    const ushort* iwb = iw_b + (size_t)l*196608;
    const ushort* owb = ow_b + (size_t)l*65536;
    const ushort* w1b = w1_b + (size_t)l*131072;
    const ushort* w2b = w2_b + (size_t)l*131072;
    float* slot = bnslots + (size_t)l*1536;

    // SAGE fused GEMM over [agg|H], K=512, +H resid, BN1 stats
    k_aggregate<<<N_NODES,256,0,stream>>>(hwb, offs, csr, inv_deg);
    k_mm<false,true,true,true,false,true><<<dim3(4,64),256,0,stream>>>(
        hwb, swb, sage_bl + l*DIM, H, locC, nullptr, slot, slot+256,
        N_NODES, DIM, 512, 512, 0);

    // attention: qkv from H (right half of hwb, lda=512), flash, out-proj
    k_mm<false,false,true,false,true,false><<<dim3(12,64),256,0,stream>>>(
        hwb+256, iwb, attn_ib + l*3*DIM, nullptr, nullptr, qkvb,
        nullptr, nullptr, N_NODES, 3*DIM, DIM, 512, 768);
    k_attn<<<1024,256,0,stream>>>(qkvb, attnOb);
    k_mm<false,true,true,true,false,true><<<dim3(4,64),256,0,stream>>>(
        attnOb, owb, attn_ob + l*DIM, H, globC, nullptr, slot+512, slot+768,
        N_NODES, DIM, DIM, DIM, 0);

    // comb = BN1(loc) + BN2(glob)
    k_apply12<<<N_NODES,256,0,stream>>>(locC, globC, slot,
        n1_w + l*DIM, n1_b + l*DIM, n2_w + l*DIM, n2_b + l*DIM, combF, combb);

    // MLP
    k_mm<true,false,true,false,true,false><<<dim3(8,64),256,0,stream>>>(
        combb, w1b, mlp_b1 + l*DFF, nullptr, nullptr, hidb, nullptr, nullptr,
        N_NODES, DFF, DIM, DIM, 512);
    k_mm<false,true,true,true,false,true><<<dim3(4,64),256,0,stream>>>(
        hidb, w2b, mlp_b2 + l*DIM, combF, globC, nullptr, slot+1024, slot+1280,
        N_NODES, DIM, 512, 512, 0);

    // BN3 + outer BN + relu + residual -> H, hwb right half
    k_apply3o<<<N_NODES,256,0,stream>>>(globC, slot, n3_w + l*DIM, n3_b + l*DIM,
        bn_w + l*DIM, bn_b + l*DIM, H, hwb+256);
  }

  k_pool<<<dim3(BGRAPH, NPG/64),256,0,stream>>>(H, pooled);
  k_out<<<1,512,0,stream>>>(pooled, w_out, b_out, (float*)d_out);
}

// Round 5
// 325.035 us; speedup vs baseline: 4.8048x; 1.0158x over previous
//
#include <hip/hip_runtime.h>
#include <hip/hip_bf16.h>

#define N_NODES 8192
#define BGRAPH 8
#define NPG 1024
#define DIM 256
#define NH 8
#define DHEAD 32
#define NLAYERS 2
#define INC 128
#define OUTD 64
#define NEDGE 262144
#define DFF 512
#define EPS 1e-5f

typedef __attribute__((ext_vector_type(4))) float f32x4;
typedef __attribute__((ext_vector_type(8))) short s16x8;
typedef __attribute__((ext_vector_type(4))) ushort u16x4;

__device__ __forceinline__ float b2f(ushort u){
  unsigned v = ((unsigned)u) << 16;
  return __builtin_bit_cast(float, v);
}
__device__ __forceinline__ ushort f2b(float f){
  unsigned u = __builtin_bit_cast(unsigned, f);
  u += 0x7fffu + ((u >> 16) & 1u);
  return (ushort)(u >> 16);
}
// async global->LDS, 16B per lane; lds base must be wave-uniform (HW adds lane*16)
__device__ __forceinline__ void gload16(const void* g, void* l){
  __builtin_amdgcn_global_load_lds(
    (const __attribute__((address_space(1))) void*)g,
    (__attribute__((address_space(3))) void*)l,
    16, 0, 0);
}

// ---------------------------------------------------------------------------
// Graph setup
// ---------------------------------------------------------------------------
__global__ void k_count_deg(const int* __restrict__ dst, int* __restrict__ deg){
  int i = blockIdx.x*blockDim.x + threadIdx.x;
  int stride = gridDim.x*blockDim.x;
  for(; i<NEDGE; i+=stride) atomicAdd(&deg[dst[i]], 1);
}
// scan + inv_deg in one kernel (single block, 1024 threads)
__global__ void k_scan(const int* __restrict__ deg, int* __restrict__ offs,
                       float* __restrict__ inv_deg){
  __shared__ int s[1024];
  int t = threadIdx.x;
  int base = t*8;
  int loc[8]; int acc=0;
  #pragma unroll
  for(int j=0;j<8;j++){
    int dv = deg[base+j];
    inv_deg[base+j] = 1.0f/(float)(dv>0?dv:1);
    loc[j]=acc; acc += dv;
  }
  s[t]=acc;
  __syncthreads();
  for(int d=1; d<1024; d<<=1){
    int v = (t>=d)? s[t-d] : 0;
    __syncthreads();
    if(t>=d) s[t]+=v;
    __syncthreads();
  }
  int pre = (t>0)? s[t-1] : 0;
  #pragma unroll
  for(int j=0;j<8;j++) offs[base+j] = pre + loc[j];
  if(t==1023) offs[N_NODES] = s[1023];
}
__global__ void k_fill_csr(const int* __restrict__ src, const int* __restrict__ dst,
                           const int* __restrict__ offs, int* __restrict__ cursor,
                           int* __restrict__ csr){
  int i = blockIdx.x*blockDim.x + threadIdx.x;
  int stride = gridDim.x*blockDim.x;
  for(; i<NEDGE; i+=stride){
    int d = dst[i];
    int p = atomicAdd(&cursor[d], 1);
    csr[offs[d]+p] = src[i];
  }
}

// mean-aggregate: one node per WAVE, lane owns 4 channels (8B loads),
// neighbor loop unrolled x4 (4 independent accumulators). No LDS/barriers.
__global__ __launch_bounds__(256) void k_aggregate(ushort* __restrict__ hwb,
    const int* __restrict__ offs, const int* __restrict__ csr,
    const float* __restrict__ inv_deg){
  int n = blockIdx.x*4 + (threadIdx.x>>6);
  int lane = threadIdx.x & 63;
  int beg = offs[n], end = offs[n+1];
  f32x4 a0 = {0,0,0,0}, a1 = {0,0,0,0}, a2 = {0,0,0,0}, a3 = {0,0,0,0};
  int i = beg;
  for(; i+4<=end; i+=4){
    int j0=csr[i], j1=csr[i+1], j2=csr[i+2], j3=csr[i+3];
    u16x4 v0 = *(const u16x4*)(hwb + (size_t)j0*512 + 256 + lane*4);
    u16x4 v1 = *(const u16x4*)(hwb + (size_t)j1*512 + 256 + lane*4);
    u16x4 v2 = *(const u16x4*)(hwb + (size_t)j2*512 + 256 + lane*4);
    u16x4 v3 = *(const u16x4*)(hwb + (size_t)j3*512 + 256 + lane*4);
    #pragma unroll
    for(int c=0;c<4;c++){ a0[c]+=b2f(v0[c]); a1[c]+=b2f(v1[c]);
                          a2[c]+=b2f(v2[c]); a3[c]+=b2f(v3[c]); }
  }
  for(; i<end; ++i){
    int j0=csr[i];
    u16x4 v0 = *(const u16x4*)(hwb + (size_t)j0*512 + 256 + lane*4);
    #pragma unroll
    for(int c=0;c<4;c++) a0[c]+=b2f(v0[c]);
  }
  float inv = inv_deg[n];
  u16x4 outv;
  #pragma unroll
  for(int c=0;c<4;c++) outv[c] = f2b((a0[c]+a1[c]+a2[c]+a3[c])*inv);
  *(u16x4*)(hwb + (size_t)n*512 + lane*4) = outv;
}

// ---------------------------------------------------------------------------
// bf16 MFMA GEMM: C[M,Nc] = A[M,K] @ W[Nc,K]^T (+bias)(+resid f32|bf16)
// -> f32 and/or bf16, optional fused BN stats. lda-aware.
// 64x64 tile, BK=64, 256 thr = 4 waves (2x2), each wave 32x32 (2x2 frags)
// ---------------------------------------------------------------------------
template<bool RELU, bool RESID, bool RESIDB, bool BIAS, bool WF32, bool WBF, bool STATS>
__global__ __launch_bounds__(256) void k_mm(const ushort* __restrict__ A,
    const ushort* __restrict__ W, const float* __restrict__ bias,
    const float* __restrict__ resid, const ushort* __restrict__ residb,
    float* __restrict__ Cf, ushort* __restrict__ Cb,
    float* __restrict__ gS, float* __restrict__ gQ,
    int M, int Nc, int K, int lda, int ldcb)
{
  __shared__ ushort As[64*64];   // 8KB
  __shared__ ushort Bs[64*64];   // 8KB
  __shared__ float sredS[64];
  __shared__ float sredQ[64];
  const int tid = threadIdx.x;
  const int lane = tid & 63, wave = tid >> 6;
  const int l15 = lane & 15, l4 = lane >> 4;
  const int bm = blockIdx.y*64, bn = blockIdx.x*64;
  const int wr = wave >> 1, wc = wave & 1;
  f32x4 acc[2][2] = {};

  for(int kt=0; kt<K; kt+=64){
    __syncthreads();
    #pragma unroll
    for(int it=0; it<2; ++it){
      int c = (wave*2+it)*64 + lane;
      int row = c >> 3, q = c & 7;
      int qs = q ^ (row & 7);
      const ushort* g = A + (size_t)(bm+row)*lda + kt + qs*8;
      gload16(g, (char*)As + (wave*2+it)*1024);
    }
    #pragma unroll
    for(int it=0; it<2; ++it){
      int c = (wave*2+it)*64 + lane;
      int row = c >> 3, q = c & 7;
      int qs = q ^ (row & 7);
      const ushort* g = W + (size_t)(bn+row)*K + kt + qs*8;
      gload16(g, (char*)Bs + (wave*2+it)*1024);
    }
    __syncthreads();
    #pragma unroll
    for(int kk=0; kk<2; ++kk){
      s16x8 af[2], bfr[2];
      #pragma unroll
      for(int mi=0; mi<2; ++mi){
        int row = wr*32 + mi*16 + l15;
        int col = (kk*64 + l4*16) ^ ((row & 7) << 4);
        af[mi] = *(const s16x8*)((const char*)As + row*128 + col);
      }
      #pragma unroll
      for(int nj=0; nj<2; ++nj){
        int row = wc*32 + nj*16 + l15;
        int col = (kk*64 + l4*16) ^ ((row & 7) << 4);
        bfr[nj] = *(const s16x8*)((const char*)Bs + row*128 + col);
      }
      #pragma unroll
      for(int mi=0; mi<2; ++mi)
        #pragma unroll
        for(int nj=0; nj<2; ++nj)
          acc[mi][nj] = __builtin_amdgcn_mfma_f32_16x16x32_bf16(af[mi], bfr[nj], acc[mi][nj], 0,0,0);
    }
  }
  float sloc[2] = {0.f,0.f}, qloc[2] = {0.f,0.f};
  #pragma unroll
  for(int mi=0; mi<2; ++mi){
    #pragma unroll
    for(int nj=0; nj<2; ++nj){
      int col = bn + wc*32 + nj*16 + l15;
      float bv = BIAS ? bias[col] : 0.f;
      #pragma unroll
      for(int r=0; r<4; ++r){
        int row = bm + wr*32 + mi*16 + l4*4 + r;
        size_t off = (size_t)row*Nc + col;
        float v = acc[mi][nj][r] + bv;
        if(RESID)  v += resid[off];
        if(RESIDB) v += b2f(residb[off]);
        if(RELU)   v = fmaxf(v, 0.f);
        if(WF32)   Cf[off] = v;
        if(WBF)    Cb[(size_t)row*ldcb + col] = f2b(v);
        if(STATS){ sloc[nj] += v; qloc[nj] += v*v; }
      }
    }
  }
  if(STATS){
    if(tid < 64){ sredS[tid]=0.f; sredQ[tid]=0.f; }
    __syncthreads();
    int c0 = wc*32 + l15;
    atomicAdd(&sredS[c0],    sloc[0]); atomicAdd(&sredQ[c0],    qloc[0]);
    atomicAdd(&sredS[c0+16], sloc[1]); atomicAdd(&sredQ[c0+16], qloc[1]);
    __syncthreads();
    if(tid < 64){
      atomicAdd(&gS[bn+tid], sredS[tid]);
      atomicAdd(&gQ[bn+tid], sredQ[tid]);
    }
  }
}

// ---------------------------------------------------------------------------
// MFMA flash attention (verified round 3)
// ---------------------------------------------------------------------------
__global__ __launch_bounds__(256) void k_attn(const ushort* __restrict__ qkv,
                                              ushort* __restrict__ attnO)
{
  __shared__ ushort Ks[64*32];
  __shared__ ushort Vt[32*64];
  const int tid = threadIdx.x, lane = tid & 63, wave = tid >> 6;
  const int l15 = lane & 15, g = lane >> 4;
  int bid = blockIdx.x;
  int qc = bid & 15;
  int h  = (bid >> 4) & 7;
  int bg = bid >> 7;
  const int nb = bg*NPG + qc*64 + wave*16;
  const int kb = bg*NPG;

  s16x8 qf = *(const s16x8*)(qkv + (size_t)(nb + l15)*768 + h*32 + g*8);
  {
    const float scale = 0.17677669529663687f;
    #pragma unroll
    for(int i=0;i<8;i++) qf[i] = (short)f2b(b2f((ushort)qf[i]) * scale);
  }
  f32x4 o0 = {0.f,0.f,0.f,0.f}, o1 = {0.f,0.f,0.f,0.f};
  float mrun = -1e30f, lrun = 0.f;

  for(int st=0; st<16; ++st){
    __syncthreads();
    {
      int rho = tid >> 2, q = tid & 3;
      int grp = rho >> 5, r32 = rho & 31;
      int tt = r32 >> 4, wi = r32 & 15;
      int j = grp*32 + (wi >> 2)*8 + tt*4 + (wi & 3);
      int qs = q ^ ((rho >> 1) & 3);
      const ushort* gp = qkv + (size_t)(kb + st*64 + j)*768 + 256 + h*32 + qs*8;
      gload16(gp, (char*)Ks + wave*1024);
    }
    {
      int j = lane;
      s16x8 vv = *(const s16x8*)(qkv + (size_t)(kb + st*64 + j)*768 + 512 + h*32 + wave*8);
      #pragma unroll
      for(int i=0;i<8;i++){
        int d = wave*8 + i;
        Vt[d*64 + (j ^ (i<<3))] = (ushort)vv[i];
      }
    }
    __syncthreads();
    #pragma unroll
    for(int g32=0; g32<2; ++g32){
      int rho0 = g32*32 + l15;
      int rho1 = g32*32 + 16 + l15;
      s16x8 k0 = *(const s16x8*)((const char*)Ks + rho0*64 + ((g*16) ^ (((rho0>>1)&3)<<4)));
      s16x8 k1 = *(const s16x8*)((const char*)Ks + rho1*64 + ((g*16) ^ (((rho1>>1)&3)<<4)));
      f32x4 z = {0.f,0.f,0.f,0.f};
      f32x4 s0 = __builtin_amdgcn_mfma_f32_16x16x32_bf16(k0, qf, z, 0,0,0);
      f32x4 s1 = __builtin_amdgcn_mfma_f32_16x16x32_bf16(k1, qf, z, 0,0,0);
      float smax = fmaxf(fmaxf(fmaxf(s0[0],s0[1]),fmaxf(s0[2],s0[3])),
                         fmaxf(fmaxf(s1[0],s1[1]),fmaxf(s1[2],s1[3])));
      smax = fmaxf(smax, __shfl_xor(smax, 16));
      smax = fmaxf(smax, __shfl_xor(smax, 32));
      float mnew = fmaxf(mrun, smax);
      float alpha = __expf(mrun - mnew);
      float p[8];
      float ps = 0.f;
      #pragma unroll
      for(int i=0;i<4;i++){ p[i]   = __expf(s0[i]-mnew); ps += p[i]; }
      #pragma unroll
      for(int i=0;i<4;i++){ p[4+i] = __expf(s1[i]-mnew); ps += p[4+i]; }
      ps += __shfl_xor(ps, 16);
      ps += __shfl_xor(ps, 32);
      lrun = lrun*alpha + ps;
      mrun = mnew;
      #pragma unroll
      for(int r=0;r<4;r++){
        float ar = __shfl(alpha, (lane & 48) | (g*4 + r), 64);
        o0[r] *= ar; o1[r] *= ar;
      }
      s16x8 pa;
      #pragma unroll
      for(int i=0;i<8;i++) pa[i] = (short)f2b(p[i]);
      int colb = g32*64 + g*16;
      int d0 = l15, d1 = l15 + 16;
      s16x8 v0 = *(const s16x8*)((const char*)Vt + d0*128 + (colb ^ ((d0&7)<<4)));
      s16x8 v1 = *(const s16x8*)((const char*)Vt + d1*128 + (colb ^ ((d1&7)<<4)));
      o0 = __builtin_amdgcn_mfma_f32_16x16x32_bf16(pa, v0, o0, 0,0,0);
      o1 = __builtin_amdgcn_mfma_f32_16x16x32_bf16(pa, v1, o1, 0,0,0);
    }
  }
  float inv = 1.0f/lrun;
  #pragma unroll
  for(int r=0;r<4;r++){
    int q2 = g*4 + r;
    float ir = __shfl(inv, (lane & 48) | q2, 64);
    size_t nrow = (size_t)(nb + q2)*DIM + h*32;
    attnO[nrow + l15]      = f2b(o0[r]*ir);
    attnO[nrow + 16 + l15] = f2b(o1[r]*ir);
  }
}

// ---------------------------------------------------------------------------
// Fused BN applies. slot layout per layer: [s1|q1|s2|q2|s3|q3] x 256 floats
// ---------------------------------------------------------------------------
__global__ __launch_bounds__(256) void k_apply12(const float* __restrict__ locC,
    const float* __restrict__ globC, const float* __restrict__ slot,
    const float* __restrict__ n1w, const float* __restrict__ n1b,
    const float* __restrict__ n2w, const float* __restrict__ n2b,
    ushort* __restrict__ combB){
  int d = threadIdx.x;
  size_t i = (size_t)blockIdx.x*DIM + d;
  const float invn = 1.0f/N_NODES;
  float m1 = slot[d]*invn,     v1 = slot[256+d]*invn - m1*m1;
  float m2 = slot[512+d]*invn, v2 = slot[768+d]*invn - m2*m2;
  float rs1 = rsqrtf(v1+EPS), rs2 = rsqrtf(v2+EPS);
  float y1 = (locC[i]-m1)*rs1*n1w[d] + n1b[d];
  float y2 = (globC[i]-m2)*rs2*n2w[d] + n2b[d];
  combB[i] = f2b(y1 + y2);
}

// BN3 + outer BN + relu + residual (closed form: mean(BN3)=b3, var(BN3)=(rs*w3)^2*var)
__global__ __launch_bounds__(256) void k_apply3o(const float* __restrict__ x,
    const float* __restrict__ slot, const float* __restrict__ n3w,
    const float* __restrict__ n3b, const float* __restrict__ bw,
    const float* __restrict__ bb, float* __restrict__ H,
    ushort* __restrict__ hwbR){
  int d = threadIdx.x;
  size_t i = (size_t)blockIdx.x*DIM + d;
  const float invn = 1.0f/N_NODES;
  float m   = slot[1024+d]*invn;
  float var = slot[1280+d]*invn - m*m;
  float rs  = rsqrtf(var+EPS);
  float gch = rs*n3w[d];
  float rso = rsqrtf(gch*gch*var + EPS);
  float yo = (x[i]-m)*gch*rso*bw[d] + bb[d];
  float h = H[i] + fmaxf(yo, 0.f);
  H[i] = h;
  hwbR[(size_t)blockIdx.x*512 + d] = f2b(h);
}

// ---------------------------------------------------------------------------
// cast x + weights f32 -> bf16 ; SAGE weights fused as [wl|wr] along K
// ---------------------------------------------------------------------------
#define CX  1048576
#define CWI (CX+32768)
#define CSW (CWI+262144)
#define CIW (CSW+393216)
#define COW (CIW+131072)
#define CW1 (COW+262144)
#define CW2 (CW1+262144)   // total 2392064
__global__ void k_cast_all(const float* __restrict__ x, const float* __restrict__ w_in,
    const float* __restrict__ wl, const float* __restrict__ wr,
    const float* __restrict__ iw, const float* __restrict__ ow,
    const float* __restrict__ w1, const float* __restrict__ w2,
    ushort* __restrict__ dst){
  int i = blockIdx.x*256 + threadIdx.x;
  float val;
  if(i < CX)       val = x[i];
  else if(i < CWI) val = w_in[i-CX];
  else if(i < CSW){
    int j = i - CWI;
    int l = j >> 17, r = (j >> 9) & 255, k = j & 511;
    val = (k < 256) ? wl[(l<<16) + (r<<8) + k] : wr[(l<<16) + (r<<8) + (k-256)];
  }
  else if(i < CIW) val = iw[i-CSW];
  else if(i < COW) val = ow[i-CIW];
  else if(i < CW1) val = w1[i-COW];
  else             val = w2[i-CW1];
  dst[i] = f2b(val);
}

// ---------------------------------------------------------------------------
// Pooling + head
// ---------------------------------------------------------------------------
__global__ void k_pool(const float* __restrict__ h, float* __restrict__ pooled){
  int b = blockIdx.x, c = blockIdx.y, d = threadIdx.x;
  int r0 = c*64;
  float s=0.f;
  for(int i=0;i<64;i++) s += h[(size_t)(b*NPG + r0 + i)*DIM + d];
  atomicAdd(&pooled[b*DIM+d], s*(1.0f/NPG));
}
__global__ void k_out(const float* __restrict__ pooled, const float* __restrict__ w_out,
                      const float* __restrict__ b_out, float* __restrict__ out){
  int t = threadIdx.x;
  if(t >= BGRAPH*OUTD) return;
  int b = t/OUTD, oc = t%OUTD;
  float s = b_out[oc];
  for(int k=0;k<DIM;k++) s += pooled[b*DIM+k]*w_out[oc*DIM+k];
  out[t] = s;
}

// ---------------------------------------------------------------------------
// Orchestration
// ---------------------------------------------------------------------------
extern "C" void kernel_launch(void* const* d_in, const int* in_sizes, int n_in,
                              void* d_out, int out_size, void* d_ws, size_t ws_size,
                              hipStream_t stream) {
  const float* x       = (const float*)d_in[0];
  const int*   edge    = (const int*)d_in[1];
  const float* w_in    = (const float*)d_in[3];
  const float* b_in    = (const float*)d_in[4];
  const float* sage_wl = (const float*)d_in[5];
  const float* sage_bl = (const float*)d_in[6];
  const float* sage_wr = (const float*)d_in[7];
  const float* attn_iw = (const float*)d_in[8];
  const float* attn_ib = (const float*)d_in[9];
  const float* attn_ow = (const float*)d_in[10];
  const float* attn_ob = (const float*)d_in[11];
  const float* n1_w = (const float*)d_in[12];
  const float* n1_b = (const float*)d_in[13];
  const float* n2_w = (const float*)d_in[14];
  const float* n2_b = (const float*)d_in[15];
  const float* n3_w = (const float*)d_in[16];
  const float* n3_b = (const float*)d_in[17];
  const float* mlp_w1 = (const float*)d_in[18];
  const float* mlp_b1 = (const float*)d_in[19];
  const float* mlp_w2 = (const float*)d_in[20];
  const float* mlp_b2 = (const float*)d_in[21];
  const float* bn_w = (const float*)d_in[22];
  const float* bn_b = (const float*)d_in[23];
  const float* w_out = (const float*)d_in[24];
  const float* b_out = (const float*)d_in[25];

  const size_t ND = (size_t)N_NODES*DIM;        // 2,097,152
  float* ws    = (float*)d_ws;
  float* H     = ws;
  float* locC  = ws + ND;
  float* globC = ws + 2*ND;
  ushort* wsb   = (ushort*)(ws + 3*ND);
  ushort* hwb   = wsb;             // [N][512] : [agg | H] bf16
  ushort* qkvb  = wsb + 2*ND;      // 3*ND
  ushort* attnOb= wsb + 5*ND;
  ushort* combb = wsb + 6*ND;
  ushort* hidb  = wsb + 7*ND;      // [N][512]
  ushort* castb = wsb + 9*ND;
  ushort* xb     = castb;
  ushort* w_in_b = castb + CX;
  ushort* sageWb = castb + CWI;
  ushort* iw_b   = castb + CSW;
  ushort* ow_b   = castb + CIW;
  ushort* w1_b   = castb + COW;
  ushort* w2_b   = castb + CW1;
  float* mf      = (float*)(castb + CW2);
  float* inv_deg = mf;
  float* bnslots = mf + 8192;
  float* pooled  = bnslots + 3072;
  int* deg    = (int*)(pooled + 2048);
  int* cursor = deg + N_NODES;
  int* offs   = cursor + N_NODES;
  int* csr    = offs + N_NODES + 8;

  const int* esrc = edge;
  const int* edst = edge + NEDGE;

  hipMemsetAsync(bnslots, 0, (3072+2048)*sizeof(float) + 2*N_NODES*sizeof(int), stream);

  k_count_deg<<<512,256,0,stream>>>(edst, deg);
  k_scan<<<1,1024,0,stream>>>(deg, offs, inv_deg);
  k_fill_csr<<<512,256,0,stream>>>(esrc, edst, offs, cursor, csr);
  k_cast_all<<<CW2/256,256,0,stream>>>(x, w_in, sage_wl, sage_wr, attn_iw,
      attn_ow, mlp_w1, mlp_w2, castb);

  // in_proj: H(f32) + hwb right half(bf16) = x @ w_in^T + b_in
  k_mm<false,false,false,true,true,true,false><<<dim3(4,128),256,0,stream>>>(
      xb, w_in_b, b_in, nullptr, nullptr, H, hwb+256, nullptr, nullptr,
      N_NODES, DIM, INC, INC, 512);

  for(int l=0; l<NLAYERS; ++l){
    const ushort* swb = sageWb + (size_t)l*131072;   // [256][512] = [wl|wr]
    const ushort* iwb = iw_b + (size_t)l*196608;
    const ushort* owb = ow_b + (size_t)l*65536;
    const ushort* w1b = w1_b + (size_t)l*131072;
    const ushort* w2b = w2_b + (size_t)l*131072;
    float* slot = bnslots + (size_t)l*1536;

    // SAGE fused GEMM over [agg|H], K=512, +H resid, BN1 stats
    k_aggregate<<<N_NODES/4,256,0,stream>>>(hwb, offs, csr, inv_deg);
    k_mm<false,true,false,true,true,false,true><<<dim3(4,128),256,0,stream>>>(
        hwb, swb, sage_bl + l*DIM, H, nullptr, locC, nullptr, slot, slot+256,
        N_NODES, DIM, 512, 512, 0);

    // attention: qkv from H (right half of hwb, lda=512), flash, out-proj
    k_mm<false,false,false,true,false,true,false><<<dim3(12,128),256,0,stream>>>(
        hwb+256, iwb, attn_ib + l*3*DIM, nullptr, nullptr, nullptr, qkvb,
        nullptr, nullptr, N_NODES, 3*DIM, DIM, 512, 768);
    k_attn<<<1024,256,0,stream>>>(qkvb, attnOb);
    k_mm<false,true,false,true,true,false,true><<<dim3(4,128),256,0,stream>>>(
        attnOb, owb, attn_ob + l*DIM, H, nullptr, globC, nullptr, slot+512, slot+768,
        N_NODES, DIM, DIM, DIM, 0);

    // comb = BN1(loc) + BN2(glob)  (bf16 only)
    k_apply12<<<N_NODES,256,0,stream>>>(locC, globC, slot,
        n1_w + l*DIM, n1_b + l*DIM, n2_w + l*DIM, n2_b + l*DIM, combb);

    // MLP: hid = relu(comb@w1^T+b1) ; out2 = comb + hid@w2^T + b2 (+BN3 stats)
    k_mm<true,false,false,true,false,true,false><<<dim3(8,128),256,0,stream>>>(
        combb, w1b, mlp_b1 + l*DFF, nullptr, nullptr, nullptr, hidb,
        nullptr, nullptr, N_NODES, DFF, DIM, DIM, 512);
    k_mm<false,false,true,true,true,false,true><<<dim3(4,128),256,0,stream>>>(
        hidb, w2b, mlp_b2 + l*DIM, nullptr, combb, globC, nullptr,
        slot+1024, slot+1280, N_NODES, DIM, 512, 512, 0);

    // BN3 + outer BN + relu + residual -> H, hwb right half
    k_apply3o<<<N_NODES,256,0,stream>>>(globC, slot, n3_w + l*DIM, n3_b + l*DIM,
        bn_w + l*DIM, bn_b + l*DIM, H, hwb+256);
  }

  k_pool<<<dim3(BGRAPH, NPG/64),256,0,stream>>>(H, pooled);
  k_out<<<1,512,0,stream>>>(pooled, w_out, b_out, (float*)d_out);
}

// Round 6
// 310.083 us; speedup vs baseline: 5.0365x; 1.0482x over previous
//
#include <hip/hip_runtime.h>
#include <hip/hip_bf16.h>

#define N_NODES 8192
#define BGRAPH 8
#define NPG 1024
#define DIM 256
#define NH 8
#define DHEAD 32
#define NLAYERS 2
#define INC 128
#define OUTD 64
#define NEDGE 262144
#define DFF 512
#define EPS 1e-5f

typedef __attribute__((ext_vector_type(4))) float f32x4;
typedef __attribute__((ext_vector_type(8))) short s16x8;
typedef __attribute__((ext_vector_type(4))) ushort u16x4;

__device__ __forceinline__ float b2f(ushort u){
  unsigned v = ((unsigned)u) << 16;
  return __builtin_bit_cast(float, v);
}
__device__ __forceinline__ ushort f2b(float f){
  unsigned u = __builtin_bit_cast(unsigned, f);
  u += 0x7fffu + ((u >> 16) & 1u);
  return (ushort)(u >> 16);
}
// truncating pack (for non-negative P values; 1 VALU op)
__device__ __forceinline__ ushort f2b_trunc(float f){
  return (ushort)(__builtin_bit_cast(unsigned, f) >> 16);
}
// async global->LDS, 16B per lane; lds base must be wave-uniform (HW adds lane*16)
__device__ __forceinline__ void gload16(const void* g, void* l){
  __builtin_amdgcn_global_load_lds(
    (const __attribute__((address_space(1))) void*)g,
    (__attribute__((address_space(3))) void*)l,
    16, 0, 0);
}

// ---------------------------------------------------------------------------
// Graph setup
// ---------------------------------------------------------------------------
__global__ void k_count_deg(const int* __restrict__ dst, int* __restrict__ deg){
  int i = blockIdx.x*blockDim.x + threadIdx.x;
  int stride = gridDim.x*blockDim.x;
  for(; i<NEDGE; i+=stride) atomicAdd(&deg[dst[i]], 1);
}
__global__ void k_scan(const int* __restrict__ deg, int* __restrict__ offs,
                       float* __restrict__ inv_deg){
  __shared__ int s[1024];
  int t = threadIdx.x;
  int base = t*8;
  int loc[8]; int acc=0;
  #pragma unroll
  for(int j=0;j<8;j++){
    int dv = deg[base+j];
    inv_deg[base+j] = 1.0f/(float)(dv>0?dv:1);
    loc[j]=acc; acc += dv;
  }
  s[t]=acc;
  __syncthreads();
  for(int d=1; d<1024; d<<=1){
    int v = (t>=d)? s[t-d] : 0;
    __syncthreads();
    if(t>=d) s[t]+=v;
    __syncthreads();
  }
  int pre = (t>0)? s[t-1] : 0;
  #pragma unroll
  for(int j=0;j<8;j++) offs[base+j] = pre + loc[j];
  if(t==1023) offs[N_NODES] = s[1023];
}
__global__ void k_fill_csr(const int* __restrict__ src, const int* __restrict__ dst,
                           const int* __restrict__ offs, int* __restrict__ cursor,
                           int* __restrict__ csr){
  int i = blockIdx.x*blockDim.x + threadIdx.x;
  int stride = gridDim.x*blockDim.x;
  for(; i<NEDGE; i+=stride){
    int d = dst[i];
    int p = atomicAdd(&cursor[d], 1);
    csr[offs[d]+p] = src[i];
  }
}

// mean-aggregate: one node per WAVE, lane owns 4 channels (8B loads),
// neighbor loop unrolled x4. No LDS/barriers.
__global__ __launch_bounds__(256) void k_aggregate(ushort* __restrict__ hwb,
    const int* __restrict__ offs, const int* __restrict__ csr,
    const float* __restrict__ inv_deg){
  int n = blockIdx.x*4 + (threadIdx.x>>6);
  int lane = threadIdx.x & 63;
  int beg = offs[n], end = offs[n+1];
  f32x4 a0 = {0,0,0,0}, a1 = {0,0,0,0}, a2 = {0,0,0,0}, a3 = {0,0,0,0};
  int i = beg;
  for(; i+4<=end; i+=4){
    int j0=csr[i], j1=csr[i+1], j2=csr[i+2], j3=csr[i+3];
    u16x4 v0 = *(const u16x4*)(hwb + (size_t)j0*512 + 256 + lane*4);
    u16x4 v1 = *(const u16x4*)(hwb + (size_t)j1*512 + 256 + lane*4);
    u16x4 v2 = *(const u16x4*)(hwb + (size_t)j2*512 + 256 + lane*4);
    u16x4 v3 = *(const u16x4*)(hwb + (size_t)j3*512 + 256 + lane*4);
    #pragma unroll
    for(int c=0;c<4;c++){ a0[c]+=b2f(v0[c]); a1[c]+=b2f(v1[c]);
                          a2[c]+=b2f(v2[c]); a3[c]+=b2f(v3[c]); }
  }
  for(; i<end; ++i){
    int j0=csr[i];
    u16x4 v0 = *(const u16x4*)(hwb + (size_t)j0*512 + 256 + lane*4);
    #pragma unroll
    for(int c=0;c<4;c++) a0[c]+=b2f(v0[c]);
  }
  float inv = inv_deg[n];
  u16x4 outv;
  #pragma unroll
  for(int c=0;c<4;c++) outv[c] = f2b((a0[c]+a1[c]+a2[c]+a3[c])*inv);
  *(u16x4*)(hwb + (size_t)n*512 + lane*4) = outv;
}

// ---------------------------------------------------------------------------
// bf16 MFMA GEMM, 2-phase double-buffered LDS pipeline.
// C[M,Nc] = A[M,K] @ W[Nc,K]^T (+bias)(+resid f32|bf16) -> f32/bf16 (+BN stats)
// 64x64 tile, BK=64, 256 thr = 4 waves (2x2), each wave 32x32 (2x2 frags)
// ---------------------------------------------------------------------------
#define STAGE_AB(t, buf) do{ \
    int kt_ = (t)*64; \
    _Pragma("unroll") \
    for(int it=0; it<2; ++it){ \
      int c = (wave*2+it)*64 + lane; \
      int row = c >> 3, q = c & 7; \
      int qs = q ^ (row & 7); \
      gload16(A + (size_t)(bm+row)*lda + kt_ + qs*8, (char*)As + (buf)*8192 + (wave*2+it)*1024); \
      gload16(W + (size_t)(bn+row)*K   + kt_ + qs*8, (char*)Bs + (buf)*8192 + (wave*2+it)*1024); \
    } \
  }while(0)

template<bool RELU, bool RESID, bool RESIDB, bool BIAS, bool WF32, bool WBF, bool STATS>
__global__ __launch_bounds__(256) void k_mm(const ushort* __restrict__ A,
    const ushort* __restrict__ W, const float* __restrict__ bias,
    const float* __restrict__ resid, const ushort* __restrict__ residb,
    float* __restrict__ Cf, ushort* __restrict__ Cb,
    float* __restrict__ gS, float* __restrict__ gQ,
    int M, int Nc, int K, int lda, int ldcb)
{
  __shared__ ushort As[2*64*64];   // 16KB (2 bufs)
  __shared__ ushort Bs[2*64*64];   // 16KB
  __shared__ float sredS[64];
  __shared__ float sredQ[64];
  const int tid = threadIdx.x;
  const int lane = tid & 63, wave = tid >> 6;
  const int l15 = lane & 15, l4 = lane >> 4;
  const int bm = blockIdx.y*64, bn = blockIdx.x*64;
  const int wr = wave >> 1, wc = wave & 1;
  f32x4 acc[2][2] = {};
  const int nt = K >> 6;

  STAGE_AB(0, 0);
  asm volatile("s_waitcnt vmcnt(0)" ::: "memory");
  __builtin_amdgcn_s_barrier();

  int cur = 0;
  for(int t=0; t<nt; ++t){
    if(t+1 < nt) STAGE_AB(t+1, cur^1);
    #pragma unroll
    for(int kk=0; kk<2; ++kk){
      s16x8 af[2], bfr[2];
      #pragma unroll
      for(int mi=0; mi<2; ++mi){
        int row = wr*32 + mi*16 + l15;
        int col = (kk*64 + l4*16) ^ ((row & 7) << 4);
        af[mi] = *(const s16x8*)((const char*)As + cur*8192 + row*128 + col);
      }
      #pragma unroll
      for(int nj=0; nj<2; ++nj){
        int row = wc*32 + nj*16 + l15;
        int col = (kk*64 + l4*16) ^ ((row & 7) << 4);
        bfr[nj] = *(const s16x8*)((const char*)Bs + cur*8192 + row*128 + col);
      }
      #pragma unroll
      for(int mi=0; mi<2; ++mi)
        #pragma unroll
        for(int nj=0; nj<2; ++nj)
          acc[mi][nj] = __builtin_amdgcn_mfma_f32_16x16x32_bf16(af[mi], bfr[nj], acc[mi][nj], 0,0,0);
    }
    asm volatile("s_waitcnt vmcnt(0)" ::: "memory");
    __builtin_amdgcn_s_barrier();
    cur ^= 1;
  }

  float sloc[2] = {0.f,0.f}, qloc[2] = {0.f,0.f};
  #pragma unroll
  for(int mi=0; mi<2; ++mi){
    #pragma unroll
    for(int nj=0; nj<2; ++nj){
      int col = bn + wc*32 + nj*16 + l15;
      float bv = BIAS ? bias[col] : 0.f;
      #pragma unroll
      for(int r=0; r<4; ++r){
        int row = bm + wr*32 + mi*16 + l4*4 + r;
        size_t off = (size_t)row*Nc + col;
        float v = acc[mi][nj][r] + bv;
        if(RESID)  v += resid[off];
        if(RESIDB) v += b2f(residb[off]);
        if(RELU)   v = fmaxf(v, 0.f);
        if(WF32)   Cf[off] = v;
        if(WBF)    Cb[(size_t)row*ldcb + col] = f2b(v);
        if(STATS){ sloc[nj] += v; qloc[nj] += v*v; }
      }
    }
  }
  if(STATS){
    if(tid < 64){ sredS[tid]=0.f; sredQ[tid]=0.f; }
    __syncthreads();
    int c0 = wc*32 + l15;
    atomicAdd(&sredS[c0],    sloc[0]); atomicAdd(&sredQ[c0],    qloc[0]);
    atomicAdd(&sredS[c0+16], sloc[1]); atomicAdd(&sredQ[c0+16], qloc[1]);
    __syncthreads();
    if(tid < 64){
      atomicAdd(&gS[bn+tid], sredS[tid]);
      atomicAdd(&gQ[bn+tid], sredQ[tid]);
    }
  }
}

// ---------------------------------------------------------------------------
// MFMA flash attention. Merged 64-key softmax round, exp2 domain, defer-max.
// ---------------------------------------------------------------------------
__global__ __launch_bounds__(256) void k_attn(const ushort* __restrict__ qkv,
                                              ushort* __restrict__ attnO)
{
  __shared__ ushort Ks[64*32];
  __shared__ ushort Vt[32*64];
  const int tid = threadIdx.x, lane = tid & 63, wave = tid >> 6;
  const int l15 = lane & 15, g = lane >> 4;
  int bid = blockIdx.x;
  int qc = bid & 15;
  int h  = (bid >> 4) & 7;
  int bg = bid >> 7;
  const int nb = bg*NPG + qc*64 + wave*16;
  const int kb = bg*NPG;

  // Q frag (B operand); fold 1/sqrt(32) * log2(e) so scores live in log2 domain
  s16x8 qf = *(const s16x8*)(qkv + (size_t)(nb + l15)*768 + h*32 + g*8);
  {
    const float scale2 = 0.2550370703637335f; // 0.176776695... * log2(e)
    #pragma unroll
    for(int i=0;i<8;i++) qf[i] = (short)f2b(b2f((ushort)qf[i]) * scale2);
  }
  f32x4 o0 = {0.f,0.f,0.f,0.f}, o1 = {0.f,0.f,0.f,0.f};
  float mrun = -1e30f, lrun = 0.f;

  for(int st=0; st<16; ++st){
    __syncthreads();
    { // stage K: permuted rows + swizzled cols (perm makes P land in PV A-frag order)
      int rho = tid >> 2, q = tid & 3;
      int grp = rho >> 5, r32 = rho & 31;
      int tt = r32 >> 4, wi = r32 & 15;
      int j = grp*32 + (wi >> 2)*8 + tt*4 + (wi & 3);
      int qs = q ^ ((rho >> 1) & 3);
      const ushort* gp = qkv + (size_t)(kb + st*64 + j)*768 + 256 + h*32 + qs*8;
      gload16(gp, (char*)Ks + wave*1024);
    }
    { // stage V transposed [d][key], swizzled
      int j = lane;
      s16x8 vv = *(const s16x8*)(qkv + (size_t)(kb + st*64 + j)*768 + 512 + h*32 + wave*8);
      #pragma unroll
      for(int i=0;i<8;i++){
        int d = wave*8 + i;
        Vt[d*64 + (j ^ (i<<3))] = (ushort)vv[i];
      }
    }
    __syncthreads();

    // QK^T: 4 score frags over all 64 keys (swapped operands)
    f32x4 sc[4];
    __builtin_amdgcn_s_setprio(1);
    #pragma unroll
    for(int q4=0; q4<4; ++q4){
      int rho = q4*16 + l15;
      s16x8 kf = *(const s16x8*)((const char*)Ks + rho*64 + ((g*16) ^ (((rho>>1)&3)<<4)));
      f32x4 z = {0.f,0.f,0.f,0.f};
      sc[q4] = __builtin_amdgcn_mfma_f32_16x16x32_bf16(kf, qf, z, 0,0,0);
    }
    __builtin_amdgcn_s_setprio(0);

    // one online-softmax round over 64 keys (lane holds 16 scores of query l15)
    float smax = -1e30f;
    #pragma unroll
    for(int q4=0; q4<4; ++q4)
      #pragma unroll
      for(int r=0; r<4; ++r) smax = fmaxf(smax, sc[q4][r]);
    smax = fmaxf(smax, __shfl_xor(smax, 16));
    smax = fmaxf(smax, __shfl_xor(smax, 32));

    if(!__all((int)(smax <= mrun + 8.0f))){   // defer-max: rescale only on growth
      float mnew = fmaxf(mrun, smax);
      float alpha = exp2f(mrun - mnew);
      lrun *= alpha;
      #pragma unroll
      for(int r=0;r<4;r++){
        float ar = __shfl(alpha, (lane & 48) | (g*4 + r), 64);
        o0[r] *= ar; o1[r] *= ar;
      }
      mrun = mnew;
    }

    float p[16];
    float ps = 0.f;
    #pragma unroll
    for(int q4=0; q4<4; ++q4)
      #pragma unroll
      for(int r=0; r<4; ++r){
        float pv = exp2f(sc[q4][r] - mrun);
        p[q4*4+r] = pv; ps += pv;
      }
    ps += __shfl_xor(ps, 16);
    ps += __shfl_xor(ps, 32);
    lrun += ps;

    // pack P -> bf16 A-frags (truncation; P >= 0)
    s16x8 pa0, pa1;
    #pragma unroll
    for(int i=0;i<8;i++){ pa0[i] = (short)f2b_trunc(p[i]); pa1[i] = (short)f2b_trunc(p[8+i]); }

    // PV
    int colb0 = g*16, colb1 = 64 + g*16;
    int d0 = l15, d1 = l15 + 16;
    s16x8 v00 = *(const s16x8*)((const char*)Vt + d0*128 + (colb0 ^ ((d0&7)<<4)));
    s16x8 v01 = *(const s16x8*)((const char*)Vt + d1*128 + (colb0 ^ ((d1&7)<<4)));
    s16x8 v10 = *(const s16x8*)((const char*)Vt + d0*128 + (colb1 ^ ((d0&7)<<4)));
    s16x8 v11 = *(const s16x8*)((const char*)Vt + d1*128 + (colb1 ^ ((d1&7)<<4)));
    __builtin_amdgcn_s_setprio(1);
    o0 = __builtin_amdgcn_mfma_f32_16x16x32_bf16(pa0, v00, o0, 0,0,0);
    o1 = __builtin_amdgcn_mfma_f32_16x16x32_bf16(pa0, v01, o1, 0,0,0);
    o0 = __builtin_amdgcn_mfma_f32_16x16x32_bf16(pa1, v10, o0, 0,0,0);
    o1 = __builtin_amdgcn_mfma_f32_16x16x32_bf16(pa1, v11, o1, 0,0,0);
    __builtin_amdgcn_s_setprio(0);
  }
  float inv = 1.0f/lrun;
  #pragma unroll
  for(int r=0;r<4;r++){
    int q2 = g*4 + r;
    float ir = __shfl(inv, (lane & 48) | q2, 64);
    size_t nrow = (size_t)(nb + q2)*DIM + h*32;
    attnO[nrow + l15]      = f2b(o0[r]*ir);
    attnO[nrow + 16 + l15] = f2b(o1[r]*ir);
  }
}

// ---------------------------------------------------------------------------
// Fused BN applies. slot layout per layer: [s1|q1|s2|q2|s3|q3] x 256 floats
// ---------------------------------------------------------------------------
__global__ __launch_bounds__(256) void k_apply12(const float* __restrict__ locC,
    const float* __restrict__ globC, const float* __restrict__ slot,
    const float* __restrict__ n1w, const float* __restrict__ n1b,
    const float* __restrict__ n2w, const float* __restrict__ n2b,
    ushort* __restrict__ combB){
  int d = threadIdx.x;
  size_t i = (size_t)blockIdx.x*DIM + d;
  const float invn = 1.0f/N_NODES;
  float m1 = slot[d]*invn,     v1 = slot[256+d]*invn - m1*m1;
  float m2 = slot[512+d]*invn, v2 = slot[768+d]*invn - m2*m2;
  float rs1 = rsqrtf(v1+EPS), rs2 = rsqrtf(v2+EPS);
  float y1 = (locC[i]-m1)*rs1*n1w[d] + n1b[d];
  float y2 = (globC[i]-m2)*rs2*n2w[d] + n2b[d];
  combB[i] = f2b(y1 + y2);
}

// BN3 + outer BN + relu + residual (closed form: mean(BN3)=b3, var(BN3)=(rs*w3)^2*var)
__global__ __launch_bounds__(256) void k_apply3o(const float* __restrict__ x,
    const float* __restrict__ slot, const float* __restrict__ n3w,
    const float* __restrict__ n3b, const float* __restrict__ bw,
    const float* __restrict__ bb, float* __restrict__ H,
    ushort* __restrict__ hwbR){
  int d = threadIdx.x;
  size_t i = (size_t)blockIdx.x*DIM + d;
  const float invn = 1.0f/N_NODES;
  float m   = slot[1024+d]*invn;
  float var = slot[1280+d]*invn - m*m;
  float rs  = rsqrtf(var+EPS);
  float gch = rs*n3w[d];
  float rso = rsqrtf(gch*gch*var + EPS);
  float yo = (x[i]-m)*gch*rso*bw[d] + bb[d];
  float h = H[i] + fmaxf(yo, 0.f);
  H[i] = h;
  hwbR[(size_t)blockIdx.x*512 + d] = f2b(h);
}

// ---------------------------------------------------------------------------
// cast x + weights f32 -> bf16 ; SAGE weights fused as [wl|wr] along K
// ---------------------------------------------------------------------------
#define CX  1048576
#define CWI (CX+32768)
#define CSW (CWI+262144)
#define CIW (CSW+393216)
#define COW (CIW+131072)
#define CW1 (COW+262144)
#define CW2 (CW1+262144)   // total 2392064
__global__ void k_cast_all(const float* __restrict__ x, const float* __restrict__ w_in,
    const float* __restrict__ wl, const float* __restrict__ wr,
    const float* __restrict__ iw, const float* __restrict__ ow,
    const float* __restrict__ w1, const float* __restrict__ w2,
    ushort* __restrict__ dst){
  int i = blockIdx.x*256 + threadIdx.x;
  float val;
  if(i < CX)       val = x[i];
  else if(i < CWI) val = w_in[i-CX];
  else if(i < CSW){
    int j = i - CWI;
    int l = j >> 17, r = (j >> 9) & 255, k = j & 511;
    val = (k < 256) ? wl[(l<<16) + (r<<8) + k] : wr[(l<<16) + (r<<8) + (k-256)];
  }
  else if(i < CIW) val = iw[i-CSW];
  else if(i < COW) val = ow[i-CIW];
  else if(i < CW1) val = w1[i-COW];
  else             val = w2[i-CW1];
  dst[i] = f2b(val);
}

// ---------------------------------------------------------------------------
// Pooling + head
// ---------------------------------------------------------------------------
__global__ void k_pool(const float* __restrict__ h, float* __restrict__ pooled){
  int b = blockIdx.x, c = blockIdx.y, d = threadIdx.x;
  int r0 = c*64;
  float s=0.f;
  for(int i=0;i<64;i++) s += h[(size_t)(b*NPG + r0 + i)*DIM + d];
  atomicAdd(&pooled[b*DIM+d], s*(1.0f/NPG));
}
__global__ void k_out(const float* __restrict__ pooled, const float* __restrict__ w_out,
                      const float* __restrict__ b_out, float* __restrict__ out){
  int t = threadIdx.x;
  if(t >= BGRAPH*OUTD) return;
  int b = t/OUTD, oc = t%OUTD;
  float s = b_out[oc];
  for(int k=0;k<DIM;k++) s += pooled[b*DIM+k]*w_out[oc*DIM+k];
  out[t] = s;
}

// ---------------------------------------------------------------------------
// Orchestration
// ---------------------------------------------------------------------------
extern "C" void kernel_launch(void* const* d_in, const int* in_sizes, int n_in,
                              void* d_out, int out_size, void* d_ws, size_t ws_size,
                              hipStream_t stream) {
  const float* x       = (const float*)d_in[0];
  const int*   edge    = (const int*)d_in[1];
  const float* w_in    = (const float*)d_in[3];
  const float* b_in    = (const float*)d_in[4];
  const float* sage_wl = (const float*)d_in[5];
  const float* sage_bl = (const float*)d_in[6];
  const float* sage_wr = (const float*)d_in[7];
  const float* attn_iw = (const float*)d_in[8];
  const float* attn_ib = (const float*)d_in[9];
  const float* attn_ow = (const float*)d_in[10];
  const float* attn_ob = (const float*)d_in[11];
  const float* n1_w = (const float*)d_in[12];
  const float* n1_b = (const float*)d_in[13];
  const float* n2_w = (const float*)d_in[14];
  const float* n2_b = (const float*)d_in[15];
  const float* n3_w = (const float*)d_in[16];
  const float* n3_b = (const float*)d_in[17];
  const float* mlp_w1 = (const float*)d_in[18];
  const float* mlp_b1 = (const float*)d_in[19];
  const float* mlp_w2 = (const float*)d_in[20];
  const float* mlp_b2 = (const float*)d_in[21];
  const float* bn_w = (const float*)d_in[22];
  const float* bn_b = (const float*)d_in[23];
  const float* w_out = (const float*)d_in[24];
  const float* b_out = (const float*)d_in[25];

  const size_t ND = (size_t)N_NODES*DIM;        // 2,097,152
  float* ws    = (float*)d_ws;
  float* H     = ws;
  float* locC  = ws + ND;
  float* globC = ws + 2*ND;
  ushort* wsb   = (ushort*)(ws + 3*ND);
  ushort* hwb   = wsb;             // [N][512] : [agg | H] bf16
  ushort* qkvb  = wsb + 2*ND;      // 3*ND
  ushort* attnOb= wsb + 5*ND;
  ushort* combb = wsb + 6*ND;
  ushort* hidb  = wsb + 7*ND;      // [N][512]
  ushort* castb = wsb + 9*ND;
  ushort* xb     = castb;
  ushort* w_in_b = castb + CX;
  ushort* sageWb = castb + CWI;
  ushort* iw_b   = castb + CSW;
  ushort* ow_b   = castb + CIW;
  ushort* w1_b   = castb + COW;
  ushort* w2_b   = castb + CW1;
  float* mf      = (float*)(castb + CW2);
  float* inv_deg = mf;
  float* bnslots = mf + 8192;
  float* pooled  = bnslots + 3072;
  int* deg    = (int*)(pooled + 2048);
  int* cursor = deg + N_NODES;
  int* offs   = cursor + N_NODES;
  int* csr    = offs + N_NODES + 8;

  const int* esrc = edge;
  const int* edst = edge + NEDGE;

  hipMemsetAsync(bnslots, 0, (3072+2048)*sizeof(float) + 2*N_NODES*sizeof(int), stream);

  k_count_deg<<<512,256,0,stream>>>(edst, deg);
  k_scan<<<1,1024,0,stream>>>(deg, offs, inv_deg);
  k_fill_csr<<<512,256,0,stream>>>(esrc, edst, offs, cursor, csr);
  k_cast_all<<<CW2/256,256,0,stream>>>(x, w_in, sage_wl, sage_wr, attn_iw,
      attn_ow, mlp_w1, mlp_w2, castb);

  // in_proj: H(f32) + hwb right half(bf16) = x @ w_in^T + b_in
  k_mm<false,false,false,true,true,true,false><<<dim3(4,128),256,0,stream>>>(
      xb, w_in_b, b_in, nullptr, nullptr, H, hwb+256, nullptr, nullptr,
      N_NODES, DIM, INC, INC, 512);

  for(int l=0; l<NLAYERS; ++l){
    const ushort* swb = sageWb + (size_t)l*131072;   // [256][512] = [wl|wr]
    const ushort* iwb = iw_b + (size_t)l*196608;
    const ushort* owb = ow_b + (size_t)l*65536;
    const ushort* w1b = w1_b + (size_t)l*131072;
    const ushort* w2b = w2_b + (size_t)l*131072;
    float* slot = bnslots + (size_t)l*1536;

    // SAGE fused GEMM over [agg|H], K=512, +H resid, BN1 stats
    k_aggregate<<<N_NODES/4,256,0,stream>>>(hwb, offs, csr, inv_deg);
    k_mm<false,true,false,true,true,false,true><<<dim3(4,128),256,0,stream>>>(
        hwb, swb, sage_bl + l*DIM, H, nullptr, locC, nullptr, slot, slot+256,
        N_NODES, DIM, 512, 512, 0);

    // attention: qkv from H (right half of hwb, lda=512), flash, out-proj
    k_mm<false,false,false,true,false,true,false><<<dim3(12,128),256,0,stream>>>(
        hwb+256, iwb, attn_ib + l*3*DIM, nullptr, nullptr, nullptr, qkvb,
        nullptr, nullptr, N_NODES, 3*DIM, DIM, 512, 768);
    k_attn<<<1024,256,0,stream>>>(qkvb, attnOb);
    k_mm<false,true,false,true,true,false,true><<<dim3(4,128),256,0,stream>>>(
        attnOb, owb, attn_ob + l*DIM, H, nullptr, globC, nullptr, slot+512, slot+768,
        N_NODES, DIM, DIM, DIM, 0);

    // comb = BN1(loc) + BN2(glob)  (bf16 only)
    k_apply12<<<N_NODES,256,0,stream>>>(locC, globC, slot,
        n1_w + l*DIM, n1_b + l*DIM, n2_w + l*DIM, n2_b + l*DIM, combb);

    // MLP: hid = relu(comb@w1^T+b1) ; out2 = comb + hid@w2^T + b2 (+BN3 stats)
    k_mm<true,false,false,true,false,true,false><<<dim3(8,128),256,0,stream>>>(
        combb, w1b, mlp_b1 + l*DFF, nullptr, nullptr, nullptr, hidb,
        nullptr, nullptr, N_NODES, DFF, DIM, DIM, 512);
    k_mm<false,false,true,true,true,false,true><<<dim3(4,128),256,0,stream>>>(
        hidb, w2b, mlp_b2 + l*DIM, nullptr, combb, globC, nullptr,
        slot+1024, slot+1280, N_NODES, DIM, 512, 512, 0);

    // BN3 + outer BN + relu + residual -> H, hwb right half
    k_apply3o<<<N_NODES,256,0,stream>>>(globC, slot, n3_w + l*DIM, n3_b + l*DIM,
        bn_w + l*DIM, bn_b + l*DIM, H, hwb+256);
  }

  k_pool<<<dim3(BGRAPH, NPG/64),256,0,stream>>>(H, pooled);
  k_out<<<1,512,0,stream>>>(pooled, w_out, b_out, (float*)d_out);
}